// Round 5
// baseline (286.983 us; speedup 1.0000x reference)
//
#include <hip/hip_runtime.h>

// Problem constants (match reference)
#define DHW   (128*128*128)        // 2^21
#define CDHW  (4*DHW)              // 2^23
#define NTOT  (2*CDHW)             // 2^24 = 16,777,216
#define NACC  4096                 // one accumulator slot per erode block

// erode2 tiling (128-thread blocks): full x-row (32 f4), 4 owned y-rows,
// 8 owned z-planes. Small blocks -> 7 blocks/CU (LDS 22.6 KB), 2-wave
// barrier scope, 4096 independent blocks: latency chains interleave.
#define ROW4     32
#define IN_ROWS  8                 // 4 + 2*2 y-halo
#define S1_ROWS  6                 // 4 + 2*1
#define IN_P4    (IN_ROWS*ROW4)    // 256 f4 / input plane
#define S1_P4    (S1_ROWS*ROW4)    // 192 f4 / s1 plane
#define SLOT4(z) (((z)+8)&3)       // input ring: 4 slots
#define SLOT2(z) (((z)+8)&1)       // s1 ring: 2 slots

// ---------------------------------------------------------------------------
// Fused pass 0: softmax + (p - onehot)^2 on the fly during staging, then TWO
// erosion steps. Each block owns one (b,c) spatial tile but reads all four
// channel tiles + tgt. Channel-sibling XCD swizzle -> sibling reads L2-merge
// (verified R3: FETCH 50 MB). Softmax owned-channel-relative:
// p_c = 1/(1 + sum_{j!=c} exp(v_j - v_c)).
// Also initializes accs[blockIdx.x] (plain store, slot is block-private).
// ---------------------------------------------------------------------------
__global__ __launch_bounds__(128, 4) void fused_sm_erode2_kernel(
    const float* __restrict__ in, const int* __restrict__ tgt,
    float4* __restrict__ dst,
    const float* __restrict__ kern, const float* __restrict__ bias,
    const float* __restrict__ weight, float c1, float c2,
    double* __restrict__ accs)
{
    __shared__ float4 lin[4 * IN_P4];   // 16.4 KB
    __shared__ float4 ls1[2 * S1_P4];   // 6.1 KB
    __shared__ double wsum[2];

    const int tid = threadIdx.x;
    // channel-sibling XCD swizzle: x = XCD, c within, spatial s per XCD
    const int x  = blockIdx.x & 7;
    const int q  = blockIdx.x >> 3;     // 0..511
    const int c  = q & 3;
    const int s  = q >> 2;              // 0..127
    const int t  = x * 128 + s;         // spatial tile id 0..1023
    const int y0 = (t & 31) << 2;
    const int zb = ((t >> 5) & 15) << 3;
    const int b  = t >> 9;
    const int bc = b * 4 + c;

    const float4* in4 = (const float4*)in;
    const int4*   tg4 = (const int4*)tgt;
    const size_t  chb = ((size_t)(b * 4)) << 19;   // channel-0 slab of batch b
    const size_t  co0 = chb + ((size_t)c << 19);   // owned channel first
    const size_t  co1 = chb + ((size_t)((c + 1) & 3) << 19);
    const size_t  co2 = chb + ((size_t)((c + 2) & 3) << 19);
    const size_t  co3 = chb + ((size_t)((c + 3) & 3) << 19);
    float4*       dp  = dst + ((size_t)bc << 19);
    const float wk = kern[13];          // all 7 taps equal
    const float bs = bias[c];

    const int col  = tid & 31;
    const int trow = tid >> 5;          // 0..3

    // ---- commit maps (input rows 0..7 <-> gy = y0+row-2) ----
    const int  gy0  = y0 + trow - 2;               // rows 0..3
    const bool lv0  = ((unsigned)gy0 < 128u);
    const int  off0 = (lv0 ? gy0 : 0) * 32 + col;
    const int  gy1  = y0 + trow + 2;               // rows 4..7
    const bool lv1  = ((unsigned)gy1 < 128u);
    const int  off1 = (lv1 ? gy1 : 0) * 32 + col;

    // ---- s1 ragged rows {0,5} on tid<64 (primary row trow+1 mask-free) ----
    const bool  sact1 = (tid < 64);
    const int   sr  = (tid < 32) ? 0 : 5;
    const float m1  = ((unsigned)(y0 + sr - 1) < 128u) ? 1.f : 0.f;
    const int   ci1 = (sr + 1) * 32 + (tid & 31);  // input center for row sr
    const int   so1 = sr * 32 + (tid & 31);        // s1-plane store index

    const float lmask = (col == 0)  ? 0.f : 1.f;   // x=0 edge
    const float rmask = (col == 31) ? 0.f : 1.f;   // x=127 edge

    const int go4 = (y0 + trow) * 32 + col;        // owned global f4 offset

    const float4 f4z = make_float4(0.f, 0.f, 0.f, 0.f);
    float4 A00 = f4z, A01 = f4z, A02 = f4z, A03 = f4z;
    float4 A10 = f4z, A11 = f4z, A12 = f4z, A13 = f4z;
    int4   T0 = make_int4(0,0,0,0), T1 = make_int4(0,0,0,0);
    bool   ok0 = false, ok1 = false;
    float4 s_m = f4z, s_c = f4z, s_p = f4z;        // s1 chain (row trow+1)

    auto prefetch = [&](int L) {
        const bool zok = ((unsigned)L < 128u);
        ok0 = zok && lv0;
        ok1 = zok && lv1;
        if (ok0) {
            size_t o = (size_t)(L << 12) + off0;
            A00 = in4[co0 + o];
            A01 = in4[co1 + o];
            A02 = in4[co2 + o];
            A03 = in4[co3 + o];
            T0  = tg4[((size_t)b << 19) + o];
        }
        if (ok1) {
            size_t o = (size_t)(L << 12) + off1;
            A10 = in4[co0 + o];
            A11 = in4[co1 + o];
            A12 = in4[co2 + o];
            A13 = in4[co3 + o];
            T1  = tg4[((size_t)b << 19) + o];
        }
    };
    // softmax + onehot-diff + square; B0 is the OWNED channel.
    auto op_one = [&](const float4& B0, const float4& B1, const float4& B2,
                      const float4& B3, const int4& T) -> float4 {
        float4 r;
        #define OP1(K)                                                         \
        {                                                                      \
            float vc = B0.K;                                                   \
            float sm = 1.0f + __expf(B1.K - vc) + __expf(B2.K - vc)            \
                            + __expf(B3.K - vc);                               \
            float d  = __builtin_amdgcn_rcpf(sm) - ((T.K == c) ? 1.0f : 0.0f); \
            r.K = d * d;                                                       \
        }
        OP1(x) OP1(y) OP1(z) OP1(w)
        #undef OP1
        return r;
    };
    auto commit = [&](int L) {
        float4* sl = lin + SLOT4(L) * IN_P4;
        float4 v0 = f4z, v1 = f4z;
        if (ok0) v0 = op_one(A00, A01, A02, A03, T0);
        if (ok1) v1 = op_one(A10, A11, A12, A13, T1);
        sl[tid] = v0;                   // rows 0..3
        sl[128 + tid] = v1;             // rows 4..7
    };
    auto s1one = [&](const float4* pzm, const float4* pzc, const float4* pzp,
                     int ci, float ym) -> float4 {
        float4 qC = pzc[ci];
        float4 qU = pzc[ci - 32];
        float4 qD = pzc[ci + 32];
        float4 qm = pzm[ci];
        float4 qp = pzp[ci];
        float lf = __shfl_up(qC.w, 1, 64)   * lmask;
        float rt = __shfl_down(qC.x, 1, 64) * rmask;
        float4 v;
        v.x = fmaxf((qC.x + lf   + qC.y + qU.x + qD.x + qm.x + qp.x) * wk + bs, 0.f) * ym;
        v.y = fmaxf((qC.y + qC.x + qC.z + qU.y + qD.y + qm.y + qp.y) * wk + bs, 0.f) * ym;
        v.z = fmaxf((qC.z + qC.y + qC.w + qU.z + qD.z + qm.z + qp.z) * wk + bs, 0.f) * ym;
        v.w = fmaxf((qC.w + qC.z + rt   + qU.w + qD.w + qm.w + qp.w) * wk + bs, 0.f) * ym;
        return v;
    };
    auto s1_phase = [&](int z) {
        float4* o = ls1 + SLOT2(z) * S1_P4;
        float4 vnew;
        if ((unsigned)z < 128u) {
            const float4* pzm = lin + SLOT4(z - 1) * IN_P4;
            const float4* pzc = lin + SLOT4(z)     * IN_P4;
            const float4* pzp = lin + SLOT4(z + 1) * IN_P4;
            vnew = s1one(pzm, pzc, pzp, tid + 64, 1.f);   // input row trow+2
            o[tid + 32] = vnew;                           // s1 row trow+1
            if (sact1) o[so1] = s1one(pzm, pzc, pzp, ci1, m1);
        } else {
            vnew = f4z;
            o[tid + 32] = f4z;
            if (sact1) o[so1] = f4z;
        }
        s_m = s_c; s_c = s_p; s_p = vnew;
    };

    double part = 0.0;

    // ---- prologue ----
    prefetch(zb - 2); commit(zb - 2);
    prefetch(zb - 1); commit(zb - 1);
    prefetch(zb);     commit(zb);
    prefetch(zb + 1);
    __syncthreads();
    s1_phase(zb - 1);                       // s_p = s1(zb-1)

    // ---- main loop: ONE barrier per plane ----
    for (int L = zb + 1; L <= zb + 9; ++L) {
        commit(L);                          // softmax + LDS store (slot L&3)
        __syncthreads();
        if (L <= zb + 8) prefetch(L + 1);   // loads land during compute below
        s1_phase(L - 1);                    // reads lin L-2..L; writes ls1 (L-1)&1
        const int zo = L - 2;
        if (zo >= zb) {
            const float4* su = ls1 + SLOT2(zo) * S1_P4;   // written last iter
            float4 u4 = su[tid];            // s1 row trow
            float4 d4 = su[tid + 64];       // s1 row trow+2
            float lf = __shfl_up(s_c.w, 1, 64)   * lmask;
            float rt = __shfl_down(s_c.x, 1, 64) * rmask;
            float4 v;
            v.x = fmaxf((s_c.x + lf    + s_c.y + u4.x + d4.x + s_m.x + s_p.x) * wk + bs, 0.f);
            v.y = fmaxf((s_c.y + s_c.x + s_c.z + u4.y + d4.y + s_m.y + s_p.y) * wk + bs, 0.f);
            v.z = fmaxf((s_c.z + s_c.y + s_c.w + u4.z + d4.z + s_m.z + s_p.z) * wk + bs, 0.f);
            v.w = fmaxf((s_c.w + s_c.z + rt    + u4.w + d4.w + s_m.w + s_p.w) * wk + bs, 0.f);
            dp[((size_t)zo << 12) + go4] = v;
            float pl = c1 * (s_c.x + s_c.y + s_c.z + s_c.w)
                     + c2 * (v.x   + v.y   + v.z   + v.w);
            part += (double)pl;
        }
    }

    // ---- block reduction (2 waves); slot blockIdx.x is block-private ----
    #pragma unroll
    for (int off = 32; off > 0; off >>= 1)
        part += __shfl_down(part, off, 64);
    if ((tid & 63) == 0) wsum[tid >> 6] = part;
    __syncthreads();
    if (tid == 0) {
        double tot = (wsum[0] + wsum[1]) * (double)weight[bc];
        accs[blockIdx.x] = tot;             // first writer: initializes slot
    }
}

// ---------------------------------------------------------------------------
// Kernel B: TWO fused erosion steps (passes 1..4), 128-thread blocks.
// XCD-swizzled blockIdx: each XCD owns one (b,c) slab.
// ---------------------------------------------------------------------------
__global__ __launch_bounds__(128, 4) void erode2_kernel(
    const float4* __restrict__ src, float4* __restrict__ dst,
    const float* __restrict__ kern, const float* __restrict__ bias,
    const float* __restrict__ weight, float c1, float c2,
    int store, double* __restrict__ accs)
{
    __shared__ float4 lin[4 * IN_P4];   // 16.4 KB
    __shared__ float4 ls1[2 * S1_P4];   // 6.1 KB
    __shared__ double wsum[2];

    const int tid = threadIdx.x;
    // XCD-aware bijective swizzle (4096 blocks, 4096 % 8 == 0).
    const int bid = ((blockIdx.x & 7) << 9) | (blockIdx.x >> 3);
    const int y0 = (bid & 31) << 2;
    const int zb = ((bid >> 5) & 15) << 3;
    const int bc = bid >> 9;            // b*4 + c in [0,8)

    const float4* sp = src + ((size_t)bc << 19);   // slab = 2^19 f4
    float4*       dp = dst + ((size_t)bc << 19);
    const float wk = kern[13];          // all 7 taps equal
    const float bs = bias[bc & 3];

    const int col  = tid & 31;
    const int trow = tid >> 5;          // 0..3

    const int  gy0  = y0 + trow - 2;               // rows 0..3
    const bool lv0  = ((unsigned)gy0 < 128u);
    const int  off0 = (lv0 ? gy0 : 0) * 32 + col;
    const int  gy1  = y0 + trow + 2;               // rows 4..7
    const bool lv1  = ((unsigned)gy1 < 128u);
    const int  off1 = (lv1 ? gy1 : 0) * 32 + col;

    const bool  sact1 = (tid < 64);
    const int   sr  = (tid < 32) ? 0 : 5;
    const float m1  = ((unsigned)(y0 + sr - 1) < 128u) ? 1.f : 0.f;
    const int   ci1 = (sr + 1) * 32 + (tid & 31);
    const int   so1 = sr * 32 + (tid & 31);

    const float lmask = (col == 0)  ? 0.f : 1.f;
    const float rmask = (col == 31) ? 0.f : 1.f;

    const int go4 = (y0 + trow) * 32 + col;

    const float4 f4z = make_float4(0.f, 0.f, 0.f, 0.f);
    float4 pf0 = f4z, pf1 = f4z;
    float4 s_m = f4z, s_c = f4z, s_p = f4z;

    auto prefetch = [&](int L) {
        pf0 = f4z; pf1 = f4z;
        if ((unsigned)L < 128u) {
            const float4* zp = sp + ((size_t)L << 12);
            if (lv0) pf0 = zp[off0];
            if (lv1) pf1 = zp[off1];
        }
    };
    auto commit = [&](int L) {
        float4* sl = lin + SLOT4(L) * IN_P4;
        sl[tid] = pf0;                  // rows 0..3
        sl[128 + tid] = pf1;            // rows 4..7
    };
    auto s1one = [&](const float4* pzm, const float4* pzc, const float4* pzp,
                     int ci, float ym) -> float4 {
        float4 qC = pzc[ci];
        float4 qU = pzc[ci - 32];
        float4 qD = pzc[ci + 32];
        float4 qm = pzm[ci];
        float4 qp = pzp[ci];
        float lf = __shfl_up(qC.w, 1, 64)   * lmask;
        float rt = __shfl_down(qC.x, 1, 64) * rmask;
        float4 v;
        v.x = fmaxf((qC.x + lf   + qC.y + qU.x + qD.x + qm.x + qp.x) * wk + bs, 0.f) * ym;
        v.y = fmaxf((qC.y + qC.x + qC.z + qU.y + qD.y + qm.y + qp.y) * wk + bs, 0.f) * ym;
        v.z = fmaxf((qC.z + qC.y + qC.w + qU.z + qD.z + qm.z + qp.z) * wk + bs, 0.f) * ym;
        v.w = fmaxf((qC.w + qC.z + rt   + qU.w + qD.w + qm.w + qp.w) * wk + bs, 0.f) * ym;
        return v;
    };
    auto s1_phase = [&](int z) {
        float4* o = ls1 + SLOT2(z) * S1_P4;
        float4 vnew;
        if ((unsigned)z < 128u) {
            const float4* pzm = lin + SLOT4(z - 1) * IN_P4;
            const float4* pzc = lin + SLOT4(z)     * IN_P4;
            const float4* pzp = lin + SLOT4(z + 1) * IN_P4;
            vnew = s1one(pzm, pzc, pzp, tid + 64, 1.f);
            o[tid + 32] = vnew;
            if (sact1) o[so1] = s1one(pzm, pzc, pzp, ci1, m1);
        } else {
            vnew = f4z;
            o[tid + 32] = f4z;
            if (sact1) o[so1] = f4z;
        }
        s_m = s_c; s_c = s_p; s_p = vnew;
    };

    double part = 0.0;

    prefetch(zb - 2); commit(zb - 2);
    prefetch(zb - 1); commit(zb - 1);
    prefetch(zb);     commit(zb);
    prefetch(zb + 1);
    __syncthreads();
    s1_phase(zb - 1);

    for (int L = zb + 1; L <= zb + 9; ++L) {
        commit(L);
        __syncthreads();
        if (L <= zb + 8) prefetch(L + 1);
        s1_phase(L - 1);
        const int zo = L - 2;
        if (zo >= zb) {
            const float4* su = ls1 + SLOT2(zo) * S1_P4;
            float4 u4 = su[tid];
            float4 d4 = su[tid + 64];
            float lf = __shfl_up(s_c.w, 1, 64)   * lmask;
            float rt = __shfl_down(s_c.x, 1, 64) * rmask;
            float4 v;
            v.x = fmaxf((s_c.x + lf    + s_c.y + u4.x + d4.x + s_m.x + s_p.x) * wk + bs, 0.f);
            v.y = fmaxf((s_c.y + s_c.x + s_c.z + u4.y + d4.y + s_m.y + s_p.y) * wk + bs, 0.f);
            v.z = fmaxf((s_c.z + s_c.y + s_c.w + u4.z + d4.z + s_m.z + s_p.z) * wk + bs, 0.f);
            v.w = fmaxf((s_c.w + s_c.z + rt    + u4.w + d4.w + s_m.w + s_p.w) * wk + bs, 0.f);
            if (store) dp[((size_t)zo << 12) + go4] = v;
            float pl = c1 * (s_c.x + s_c.y + s_c.z + s_c.w)
                     + c2 * (v.x   + v.y   + v.z   + v.w);
            part += (double)pl;
        }
    }

    #pragma unroll
    for (int off = 32; off > 0; off >>= 1)
        part += __shfl_down(part, off, 64);
    if ((tid & 63) == 0) wsum[tid >> 6] = part;
    __syncthreads();
    if (tid == 0) {
        double tot = (wsum[0] + wsum[1]) * (double)weight[bc];
        atomicAdd(&accs[bid], tot);         // slot initialized by fused pass 0
    }
}

// Reduce the NACC per-block accumulators -> scalar mean.
__global__ __launch_bounds__(1024) void finalize_kernel(
    const double* __restrict__ accs, float* __restrict__ out)
{
    __shared__ double wsum[16];
    double v = accs[threadIdx.x] + accs[threadIdx.x + 1024]
             + accs[threadIdx.x + 2048] + accs[threadIdx.x + 3072];
    #pragma unroll
    for (int off = 32; off > 0; off >>= 1)
        v += __shfl_down(v, off, 64);
    int lane = threadIdx.x & 63;
    int wid  = threadIdx.x >> 6;
    if (lane == 0) wsum[wid] = v;
    __syncthreads();
    if (threadIdx.x == 0) {
        double tot = 0.0;
        #pragma unroll
        for (int i = 0; i < 16; ++i) tot += wsum[i];
        out[0] = (float)(tot / (double)NTOT);
    }
}

extern "C" void kernel_launch(void* const* d_in, const int* in_sizes, int n_in,
                              void* d_out, int out_size, void* d_ws, size_t ws_size,
                              hipStream_t stream) {
    const float* in     = (const float*)d_in[0];
    const int*   tgt    = (const int*)d_in[1];
    const float* weight = (const float*)d_in[2];
    const float* kern   = (const float*)d_in[3];
    const float* bias   = (const float*)d_in[4];
    float* out = (float*)d_out;

    char* ws = (char*)d_ws;
    float* buf0 = (float*)ws;
    float* buf1 = (float*)(ws + (size_t)NTOT * sizeof(float));
    double* accs = (double*)(ws + (size_t)NTOT * 2 * sizeof(float));

    // 1) fused softmax+square+double-erosion pass 0: in -> buf0
    //    (also initializes all 4096 accs slots with c1=1, c2=4 contributions)
    fused_sm_erode2_kernel<<<4096, 128, 0, stream>>>(
        in, tgt, (float4*)buf0, kern, bias, weight, 1.0f, 4.0f, accs);

    // 2) 4 more fused double-erosion passes; last pass skips the store
    float* cur = buf0;
    float* nxt = buf1;
    for (int p = 1; p < 5; ++p) {
        float c1 = (float)((2 * p + 1) * (2 * p + 1));
        float c2 = (float)((2 * p + 2) * (2 * p + 2));
        int   store = (p < 4) ? 1 : 0;
        erode2_kernel<<<4096, 128, 0, stream>>>(
            (const float4*)cur, (float4*)nxt, kern, bias, weight, c1, c2, store, accs);
        float* t = cur; cur = nxt; nxt = t;
    }

    // 3) reduce + mean
    finalize_kernel<<<1, 1024, 0, stream>>>(accs, out);
}

// Round 6
// 163.571 us; speedup vs baseline: 1.7545x; 1.7545x over previous
//
#include <hip/hip_runtime.h>

// Problem constants (match reference)
#define DHW   (128*128*128)        // 2^21
#define CDHW  (4*DHW)              // 2^23
#define NTOT  (2*CDHW)             // 2^24 = 16,777,216
#define NACC  1024                 // one accumulator slot per erode block

// erode2 tiling: full x-row (32 f4), 8 owned y-rows, 16 owned z-planes.
#define ROW4     32
#define IN_ROWS  12                // 8 + 2*2 y-halo
#define S1_ROWS  10                // 8 + 2*1
#define IN_P4    (IN_ROWS*ROW4)    // 384 f4 / input plane
#define S1_P4    (S1_ROWS*ROW4)    // 320 f4 / s1 plane
#define SLOT4(z) (((z)+8)&3)       // input ring: 4 slots
#define SLOT2(z) (((z)+8)&1)       // s1 ring: 2 slots

// Logical tile id (flag index): fid = (bc<<7) | (tz<<4) | ty
//   ty in [0,16): 8-row y-tile;  tz in [0,8): 16-plane z-tile;  bc = b*4+c.

// ---------------------------------------------------------------------------
// Fused pass 0: softmax + (p - onehot)^2 on the fly during staging, then TWO
// erosion steps. Channel-sibling XCD swizzle -> sibling reads L2-merge
// (verified R3: FETCH 50 MB). Softmax owned-channel-relative.
// NEW: tracks whether its output tile (s2) is entirely zero and writes
// flagOut[fid] (1 = has nonzero). Erosion annihilates quickly for realistic
// inputs, so downstream passes can skip zero tiles entirely.
// Also initializes accs[blockIdx.x] (plain store, slot is block-private).
// ---------------------------------------------------------------------------
__global__ __launch_bounds__(256, 4) void fused_sm_erode2_kernel(
    const float* __restrict__ in, const int* __restrict__ tgt,
    float4* __restrict__ dst,
    const float* __restrict__ kern, const float* __restrict__ bias,
    const float* __restrict__ weight, float c1, float c2,
    double* __restrict__ accs, int* __restrict__ flagOut)
{
    __shared__ float4 lin[4 * IN_P4];   // 24.6 KB
    __shared__ float4 ls1[2 * S1_P4];   // 10.2 KB
    __shared__ double wsum[4];
    __shared__ int    snz;

    const int tid = threadIdx.x;
    // channel-sibling XCD swizzle: x = XCD, q>>2 = spatial-within-XCD, q&3 = c
    const int x  = blockIdx.x & 7;
    const int q  = blockIdx.x >> 3;
    const int c  = q & 3;
    const int t  = x * 32 + (q >> 2);   // spatial tile id 0..255
    const int y0 = (t & 15) << 3;
    const int zb = ((t >> 4) & 7) << 4;
    const int b  = (t >> 7) & 1;
    const int bc = b * 4 + c;
    const int fid = (bc << 7) | (((t >> 4) & 7) << 4) | (t & 15);

    const float4* in4 = (const float4*)in;
    const int4*   tg4 = (const int4*)tgt;
    const size_t  chb = ((size_t)(b * 4)) << 19;   // channel-0 slab of batch b
    const size_t  co0 = chb + ((size_t)c << 19);   // owned channel first
    const size_t  co1 = chb + ((size_t)((c + 1) & 3) << 19);
    const size_t  co2 = chb + ((size_t)((c + 2) & 3) << 19);
    const size_t  co3 = chb + ((size_t)((c + 3) & 3) << 19);
    float4*       dp  = dst + ((size_t)bc << 19);
    const float wk = kern[13];          // all 7 taps equal
    const float bs = bias[c];

    const int col  = tid & 31;
    const int trow = tid >> 5;

    if (tid == 0) snz = 0;

    // ---- commit maps (input rows 0..11 <-> gy = y0+row-2) ----
    const int  gy0  = y0 + trow - 2;               // rows 0..7
    const bool lv0  = ((unsigned)gy0 < 128u);
    const int  off0 = (lv0 ? gy0 : 0) * 32 + col;
    const bool act1 = (tid < 128);                 // rows 8..11
    const int  gy1  = y0 + trow + 6;
    const bool lv1  = act1 && ((unsigned)gy1 < 128u);
    const int  off1 = (lv1 ? gy1 : 0) * 32 + col;

    // ---- s1 ragged rows {0,9} on tid<64 (primary row trow+1 is mask-free) --
    const bool  sact1 = (tid < 64);
    const int   sr  = (tid < 32) ? 0 : 9;
    const float m1  = ((unsigned)(y0 + sr - 1) < 128u) ? 1.f : 0.f;
    const int   ci1 = (sr + 1) * 32 + (tid & 31);  // input center for row sr
    const int   so1 = sr * 32 + (tid & 31);        // s1-plane store index

    const float lmask = (col == 0)  ? 0.f : 1.f;   // x=0 edge
    const float rmask = (col == 31) ? 0.f : 1.f;   // x=127 edge

    const int go4 = (y0 + trow) * 32 + col;        // owned global f4 offset

    const float4 f4z = make_float4(0.f, 0.f, 0.f, 0.f);
    float4 A00 = f4z, A01 = f4z, A02 = f4z, A03 = f4z;
    float4 A10 = f4z, A11 = f4z, A12 = f4z, A13 = f4z;
    int4   T0 = make_int4(0,0,0,0), T1 = make_int4(0,0,0,0);
    bool   ok0 = false, ok1 = false;
    float4 s_m = f4z, s_c = f4z, s_p = f4z;        // s1 chain (rows trow+1)
    int    nz  = 0;

    auto prefetch = [&](int L) {
        const bool zok = ((unsigned)L < 128u);
        ok0 = zok && lv0;
        ok1 = zok && lv1;
        if (ok0) {
            size_t o = (size_t)(L << 12) + off0;
            A00 = in4[co0 + o];
            A01 = in4[co1 + o];
            A02 = in4[co2 + o];
            A03 = in4[co3 + o];
            T0  = tg4[((size_t)b << 19) + o];
        }
        if (ok1) {
            size_t o = (size_t)(L << 12) + off1;
            A10 = in4[co0 + o];
            A11 = in4[co1 + o];
            A12 = in4[co2 + o];
            A13 = in4[co3 + o];
            T1  = tg4[((size_t)b << 19) + o];
        }
    };
    // softmax + onehot-diff + square; B0 is the OWNED channel.
    auto op_one = [&](const float4& B0, const float4& B1, const float4& B2,
                      const float4& B3, const int4& T) -> float4 {
        float4 r;
        #define OP1(K)                                                         \
        {                                                                      \
            float vc = B0.K;                                                   \
            float sm = 1.0f + __expf(B1.K - vc) + __expf(B2.K - vc)            \
                            + __expf(B3.K - vc);                               \
            float d  = __builtin_amdgcn_rcpf(sm) - ((T.K == c) ? 1.0f : 0.0f); \
            r.K = d * d;                                                       \
        }
        OP1(x) OP1(y) OP1(z) OP1(w)
        #undef OP1
        return r;
    };
    auto commit = [&](int L) {
        float4* sl = lin + SLOT4(L) * IN_P4;
        float4 v0 = f4z, v1 = f4z;
        if (ok0) v0 = op_one(A00, A01, A02, A03, T0);
        if (ok1) v1 = op_one(A10, A11, A12, A13, T1);
        sl[tid] = v0;
        if (act1) sl[256 + tid] = v1;
    };
    auto s1one = [&](const float4* pzm, const float4* pzc, const float4* pzp,
                     int ci, float ym) -> float4 {
        float4 qC = pzc[ci];
        float4 qU = pzc[ci - 32];
        float4 qD = pzc[ci + 32];
        float4 qm = pzm[ci];
        float4 qp = pzp[ci];
        float lf = __shfl_up(qC.w, 1, 64)   * lmask;
        float rt = __shfl_down(qC.x, 1, 64) * rmask;
        float4 v;
        v.x = fmaxf((qC.x + lf   + qC.y + qU.x + qD.x + qm.x + qp.x) * wk + bs, 0.f) * ym;
        v.y = fmaxf((qC.y + qC.x + qC.z + qU.y + qD.y + qm.y + qp.y) * wk + bs, 0.f) * ym;
        v.z = fmaxf((qC.z + qC.y + qC.w + qU.z + qD.z + qm.z + qp.z) * wk + bs, 0.f) * ym;
        v.w = fmaxf((qC.w + qC.z + rt   + qU.w + qD.w + qm.w + qp.w) * wk + bs, 0.f) * ym;
        return v;
    };
    auto s1_phase = [&](int z) {
        float4* o = ls1 + SLOT2(z) * S1_P4;
        float4 vnew;
        if ((unsigned)z < 128u) {
            const float4* pzm = lin + SLOT4(z - 1) * IN_P4;
            const float4* pzc = lin + SLOT4(z)     * IN_P4;
            const float4* pzp = lin + SLOT4(z + 1) * IN_P4;
            vnew = s1one(pzm, pzc, pzp, tid + 64, 1.f);   // input row trow+2
            o[tid + 32] = vnew;                           // s1 row trow+1
            if (sact1) o[so1] = s1one(pzm, pzc, pzp, ci1, m1);
        } else {
            vnew = f4z;
            o[tid + 32] = f4z;
            if (sact1) o[so1] = f4z;
        }
        s_m = s_c; s_c = s_p; s_p = vnew;
    };

    double part = 0.0;

    // ---- prologue ----
    prefetch(zb - 2); commit(zb - 2);
    prefetch(zb - 1); commit(zb - 1);
    prefetch(zb);     commit(zb);
    prefetch(zb + 1);
    __syncthreads();
    s1_phase(zb - 1);                       // s_p = s1(zb-1)

    // ---- main loop: ONE barrier per plane ----
    for (int L = zb + 1; L <= zb + 17; ++L) {
        commit(L);                          // softmax + LDS store (slot L&3)
        __syncthreads();
        if (L <= zb + 16) prefetch(L + 1);  // loads land during compute below
        s1_phase(L - 1);                    // reads lin L-2..L; writes ls1 (L-1)&1
        const int zo = L - 2;
        if (zo >= zb) {
            const float4* su = ls1 + SLOT2(zo) * S1_P4;   // written last iter
            float4 u4 = su[tid];            // s1 row trow
            float4 d4 = su[tid + 64];       // s1 row trow+2
            float lf = __shfl_up(s_c.w, 1, 64)   * lmask;
            float rt = __shfl_down(s_c.x, 1, 64) * rmask;
            float4 v;
            v.x = fmaxf((s_c.x + lf    + s_c.y + u4.x + d4.x + s_m.x + s_p.x) * wk + bs, 0.f);
            v.y = fmaxf((s_c.y + s_c.x + s_c.z + u4.y + d4.y + s_m.y + s_p.y) * wk + bs, 0.f);
            v.z = fmaxf((s_c.z + s_c.y + s_c.w + u4.z + d4.z + s_m.z + s_p.z) * wk + bs, 0.f);
            v.w = fmaxf((s_c.w + s_c.z + rt    + u4.w + d4.w + s_m.w + s_p.w) * wk + bs, 0.f);
            dp[((size_t)zo << 12) + go4] = v;
            nz |= (v.x != 0.f) | (v.y != 0.f) | (v.z != 0.f) | (v.w != 0.f);
            float pl = c1 * (s_c.x + s_c.y + s_c.z + s_c.w)
                     + c2 * (v.x   + v.y   + v.z   + v.w);
            part += (double)pl;
        }
    }

    // ---- block reduction; slot blockIdx.x is private to this block ----
    #pragma unroll
    for (int off = 32; off > 0; off >>= 1)
        part += __shfl_down(part, off, 64);
    if ((tid & 63) == 0) wsum[tid >> 6] = part;
    if (__any(nz) && (tid & 63) == 0) atomicOr(&snz, 1);
    __syncthreads();
    if (tid == 0) {
        double tot = (wsum[0] + wsum[1] + wsum[2] + wsum[3]) * (double)weight[bc];
        accs[blockIdx.x] = tot;             // first writer: initializes slot
        flagOut[fid] = snz;
    }
}

// ---------------------------------------------------------------------------
// Kernel B: TWO fused erosion steps (passes 1..4). XCD-swizzled blockIdx.
// Zero-tile skipping: reads the 9 (y,z)-neighborhood flags from the previous
// pass. If all zero, the input tile+halo is exactly zero -> s1 = s2 = 0 ->
// contribute nothing, write flag 0, return (no loads/stores). Otherwise
// compute normally, substituting 0.0 for halo loads from flag-0 tiles
// (their memory was never written).
// ---------------------------------------------------------------------------
__global__ __launch_bounds__(256, 4) void erode2_kernel(
    const float4* __restrict__ src, float4* __restrict__ dst,
    const float* __restrict__ kern, const float* __restrict__ bias,
    const float* __restrict__ weight, float c1, float c2,
    int store, double* __restrict__ accs,
    const int* __restrict__ flagIn, int* __restrict__ flagOut)
{
    __shared__ float4 lin[4 * IN_P4];   // 24.6 KB
    __shared__ float4 ls1[2 * S1_P4];   // 10.2 KB
    __shared__ double wsum[4];
    __shared__ int    sf[9];
    __shared__ int    snz;

    const int tid = threadIdx.x;
    // XCD-aware bijective swizzle (1024 blocks, 1024 % 8 == 0).
    const int bid = ((blockIdx.x & 7) << 7) | (blockIdx.x >> 3);
    const int ty = bid & 15;
    const int tz = (bid >> 4) & 7;
    const int y0 = ty << 3;
    const int zb = tz << 4;
    const int bc = bid >> 7;            // b*4 + c in [0,8)

    // ---- load 3x3 neighbor flags (dz = tid/3-1, dy = tid%3-1) ----
    if (tid < 9) {
        int dy = tid % 3 - 1, dz = tid / 3 - 1;
        int yt = ty + dy, zt = tz + dz;
        int f = 0;
        if ((unsigned)yt < 16u && (unsigned)zt < 8u)
            f = flagIn[(bc << 7) | (zt << 4) | yt];
        sf[tid] = f;
    }
    if (tid == 0) snz = 0;
    __syncthreads();
    const int any = sf[0] | sf[1] | sf[2] | sf[3] | sf[4]
                  | sf[5] | sf[6] | sf[7] | sf[8];
    if (!any) {                         // input tile+halo exactly zero
        if (tid == 0) {
            flagOut[bid] = 0;           // output zero too; dst never read
        }
        return;                         // uniform exit; no loads/stores
    }

    const float4* sp = src + ((size_t)bc << 19);   // slab = 2^19 f4
    float4*       dp = dst + ((size_t)bc << 19);
    const float wk = kern[13];          // all 7 taps equal
    const float bs = bias[bc & 3];

    const int col  = tid & 31;
    const int trow = tid >> 5;

    // ---- commit maps (input rows 0..11 <-> gy = y0+row-2) ----
    const int  gy0  = y0 + trow - 2;               // rows 0..7
    const bool lv0  = ((unsigned)gy0 < 128u);
    const int  off0 = (lv0 ? gy0 : 0) * 32 + col;
    const bool act1 = (tid < 128);                 // rows 8..11
    const int  gy1  = y0 + trow + 6;
    const bool lv1  = act1 && ((unsigned)gy1 < 128u);
    const int  off1 = (lv1 ? gy1 : 0) * 32 + col;

    // per-thread y-tile offsets into sf (0..2); valid whenever lv* is true
    const int yd0 = (gy0 >> 3) - ty + 1;
    const int yd1 = (gy1 >> 3) - ty + 1;
    // bitmask over dz of "source tile nonzero" for this thread's two rows
    const int fmask0 = (sf[0 + ((unsigned)yd0 < 3u ? yd0 : 1)] ? 1 : 0)
                     | (sf[3 + ((unsigned)yd0 < 3u ? yd0 : 1)] ? 2 : 0)
                     | (sf[6 + ((unsigned)yd0 < 3u ? yd0 : 1)] ? 4 : 0);
    const int fmask1 = (sf[0 + ((unsigned)yd1 < 3u ? yd1 : 1)] ? 1 : 0)
                     | (sf[3 + ((unsigned)yd1 < 3u ? yd1 : 1)] ? 2 : 0)
                     | (sf[6 + ((unsigned)yd1 < 3u ? yd1 : 1)] ? 4 : 0);

    // ---- s1 ragged rows {0,9} on tid<64 (primary row trow+1 is mask-free) --
    const bool  sact1 = (tid < 64);
    const int   sr  = (tid < 32) ? 0 : 9;
    const float m1  = ((unsigned)(y0 + sr - 1) < 128u) ? 1.f : 0.f;
    const int   ci1 = (sr + 1) * 32 + (tid & 31);
    const int   so1 = sr * 32 + (tid & 31);

    const float lmask = (col == 0)  ? 0.f : 1.f;
    const float rmask = (col == 31) ? 0.f : 1.f;

    const int go4 = (y0 + trow) * 32 + col;

    const float4 f4z = make_float4(0.f, 0.f, 0.f, 0.f);
    float4 pf0 = f4z, pf1 = f4z;
    float4 s_m = f4z, s_c = f4z, s_p = f4z;
    int    nz  = 0;

    auto prefetch = [&](int L) {
        pf0 = f4z; pf1 = f4z;
        if ((unsigned)L < 128u) {
            const int zidx = (L >> 4) - tz + 1;        // 0..2 for valid planes
            const float4* zp = sp + ((size_t)L << 12);
            if (lv0 && ((fmask0 >> zidx) & 1)) pf0 = zp[off0];
            if (lv1 && ((fmask1 >> zidx) & 1)) pf1 = zp[off1];
        }
    };
    auto commit = [&](int L) {
        float4* sl = lin + SLOT4(L) * IN_P4;
        sl[tid] = pf0;
        if (act1) sl[256 + tid] = pf1;
    };
    auto s1one = [&](const float4* pzm, const float4* pzc, const float4* pzp,
                     int ci, float ym) -> float4 {
        float4 qC = pzc[ci];
        float4 qU = pzc[ci - 32];
        float4 qD = pzc[ci + 32];
        float4 qm = pzm[ci];
        float4 qp = pzp[ci];
        float lf = __shfl_up(qC.w, 1, 64)   * lmask;
        float rt = __shfl_down(qC.x, 1, 64) * rmask;
        float4 v;
        v.x = fmaxf((qC.x + lf   + qC.y + qU.x + qD.x + qm.x + qp.x) * wk + bs, 0.f) * ym;
        v.y = fmaxf((qC.y + qC.x + qC.z + qU.y + qD.y + qm.y + qp.y) * wk + bs, 0.f) * ym;
        v.z = fmaxf((qC.z + qC.y + qC.w + qU.z + qD.z + qm.z + qp.z) * wk + bs, 0.f) * ym;
        v.w = fmaxf((qC.w + qC.z + rt   + qU.w + qD.w + qm.w + qp.w) * wk + bs, 0.f) * ym;
        return v;
    };
    auto s1_phase = [&](int z) {
        float4* o = ls1 + SLOT2(z) * S1_P4;
        float4 vnew;
        if ((unsigned)z < 128u) {
            const float4* pzm = lin + SLOT4(z - 1) * IN_P4;
            const float4* pzc = lin + SLOT4(z)     * IN_P4;
            const float4* pzp = lin + SLOT4(z + 1) * IN_P4;
            vnew = s1one(pzm, pzc, pzp, tid + 64, 1.f);
            o[tid + 32] = vnew;
            if (sact1) o[so1] = s1one(pzm, pzc, pzp, ci1, m1);
        } else {
            vnew = f4z;
            o[tid + 32] = f4z;
            if (sact1) o[so1] = f4z;
        }
        s_m = s_c; s_c = s_p; s_p = vnew;
    };

    double part = 0.0;

    prefetch(zb - 2); commit(zb - 2);
    prefetch(zb - 1); commit(zb - 1);
    prefetch(zb);     commit(zb);
    prefetch(zb + 1);
    __syncthreads();
    s1_phase(zb - 1);

    for (int L = zb + 1; L <= zb + 17; ++L) {
        commit(L);
        __syncthreads();
        if (L <= zb + 16) prefetch(L + 1);
        s1_phase(L - 1);
        const int zo = L - 2;
        if (zo >= zb) {
            const float4* su = ls1 + SLOT2(zo) * S1_P4;
            float4 u4 = su[tid];
            float4 d4 = su[tid + 64];
            float lf = __shfl_up(s_c.w, 1, 64)   * lmask;
            float rt = __shfl_down(s_c.x, 1, 64) * rmask;
            float4 v;
            v.x = fmaxf((s_c.x + lf    + s_c.y + u4.x + d4.x + s_m.x + s_p.x) * wk + bs, 0.f);
            v.y = fmaxf((s_c.y + s_c.x + s_c.z + u4.y + d4.y + s_m.y + s_p.y) * wk + bs, 0.f);
            v.z = fmaxf((s_c.z + s_c.y + s_c.w + u4.z + d4.z + s_m.z + s_p.z) * wk + bs, 0.f);
            v.w = fmaxf((s_c.w + s_c.z + rt    + u4.w + d4.w + s_m.w + s_p.w) * wk + bs, 0.f);
            if (store) dp[((size_t)zo << 12) + go4] = v;
            nz |= (v.x != 0.f) | (v.y != 0.f) | (v.z != 0.f) | (v.w != 0.f);
            float pl = c1 * (s_c.x + s_c.y + s_c.z + s_c.w)
                     + c2 * (v.x   + v.y   + v.z   + v.w);
            part += (double)pl;
        }
    }

    #pragma unroll
    for (int off = 32; off > 0; off >>= 1)
        part += __shfl_down(part, off, 64);
    if ((tid & 63) == 0) wsum[tid >> 6] = part;
    if (__any(nz) && (tid & 63) == 0) atomicOr(&snz, 1);
    __syncthreads();
    if (tid == 0) {
        flagOut[bid] = snz;
        double tot = (wsum[0] + wsum[1] + wsum[2] + wsum[3]) * (double)weight[bc];
        atomicAdd(&accs[bid], tot);         // slot initialized by fused pass 0
    }
}

// Reduce the NACC per-block accumulators -> scalar mean.
__global__ __launch_bounds__(1024) void finalize_kernel(
    const double* __restrict__ accs, float* __restrict__ out)
{
    __shared__ double wsum[16];
    double v = accs[threadIdx.x];
    #pragma unroll
    for (int off = 32; off > 0; off >>= 1)
        v += __shfl_down(v, off, 64);
    int lane = threadIdx.x & 63;
    int wid  = threadIdx.x >> 6;
    if (lane == 0) wsum[wid] = v;
    __syncthreads();
    if (threadIdx.x == 0) {
        double tot = 0.0;
        #pragma unroll
        for (int i = 0; i < 16; ++i) tot += wsum[i];
        out[0] = (float)(tot / (double)NTOT);
    }
}

extern "C" void kernel_launch(void* const* d_in, const int* in_sizes, int n_in,
                              void* d_out, int out_size, void* d_ws, size_t ws_size,
                              hipStream_t stream) {
    const float* in     = (const float*)d_in[0];
    const int*   tgt    = (const int*)d_in[1];
    const float* weight = (const float*)d_in[2];
    const float* kern   = (const float*)d_in[3];
    const float* bias   = (const float*)d_in[4];
    float* out = (float*)d_out;

    char* ws = (char*)d_ws;
    float*  buf0   = (float*)ws;
    float*  buf1   = (float*)(ws + (size_t)NTOT * sizeof(float));
    double* accs   = (double*)(ws + (size_t)NTOT * 2 * sizeof(float));
    int*    flagsA = (int*)(ws + (size_t)NTOT * 2 * sizeof(float) + NACC * sizeof(double));
    int*    flagsB = flagsA + NACC;

    // 1) fused softmax+square+double-erosion pass 0: in -> buf0
    //    (inits accs; writes flagsA)
    fused_sm_erode2_kernel<<<1024, 256, 0, stream>>>(
        in, tgt, (float4*)buf0, kern, bias, weight, 1.0f, 4.0f, accs, flagsA);

    // 2) 4 more fused double-erosion passes with zero-tile skipping;
    //    flags ping-pong; last pass skips the store
    float* cur = buf0;
    float* nxt = buf1;
    int*   fIn = flagsA;
    int*   fOut = flagsB;
    for (int p = 1; p < 5; ++p) {
        float c1 = (float)((2 * p + 1) * (2 * p + 1));
        float c2 = (float)((2 * p + 2) * (2 * p + 2));
        int   store = (p < 4) ? 1 : 0;
        erode2_kernel<<<1024, 256, 0, stream>>>(
            (const float4*)cur, (float4*)nxt, kern, bias, weight, c1, c2,
            store, accs, fIn, fOut);
        float* tb = cur; cur = nxt; nxt = tb;
        int*   tf = fIn; fIn = fOut; fOut = tf;
    }

    // 3) reduce + mean
    finalize_kernel<<<1, 1024, 0, stream>>>(accs, out);
}

// Round 7
// 155.344 us; speedup vs baseline: 1.8474x; 1.0530x over previous
//
#include <hip/hip_runtime.h>

// Problem constants (match reference)
#define DHW   (128*128*128)        // 2^21
#define CDHW  (4*DHW)              // 2^23
#define NTOT  (2*CDHW)             // 2^24 = 16,777,216
#define NACC  1024                 // one accumulator slot per erode block

// erode2 tiling: full x-row (32 f4), 8 owned y-rows, 16 owned z-planes.
#define ROW4     32
#define IN_ROWS  12                // 8 + 2*2 y-halo
#define S1_ROWS  10                // 8 + 2*1
#define IN_P4    (IN_ROWS*ROW4)    // 384 f4 / input plane
#define S1_P4    (S1_ROWS*ROW4)    // 320 f4 / s1 plane
#define SLOT4(z) (((z)+8)&3)       // input ring: 4 slots
#define SLOT2(z) (((z)+8)&1)       // s1 ring: 2 slots

// Flag word per tile: 16-bit mask, bit (z-zb) = plane z has a nonzero.
// fid = (bc<<7) | (tz<<4) | ty.

// ---------------------------------------------------------------------------
// Fused pass 0: softmax + (p-onehot)^2 during staging, then TWO erosion
// steps. Channel-sibling XCD swizzle (R3: sibling reads L2-merge, FETCH
// ~50 MB). Softmax owned-channel-relative (3 exps).
// NEW: per-plane nonzero vote (LDS atomicOr, published by the next plane's
// barrier) -> s2 planes stored ONLY if nonzero (erosion kills ~everything,
// so WRITE ~0), and the 16-bit plane mask is the tile flag.
// Also initializes accs[blockIdx.x].
// ---------------------------------------------------------------------------
__global__ __launch_bounds__(256, 4) void fused_sm_erode2_kernel(
    const float* __restrict__ in, const int* __restrict__ tgt,
    float4* __restrict__ dst,
    const float* __restrict__ kern, const float* __restrict__ bias,
    const float* __restrict__ weight, float c1, float c2,
    double* __restrict__ accs, int* __restrict__ flagOut)
{
    __shared__ float4 lin[4 * IN_P4];   // 24.6 KB
    __shared__ float4 ls1[2 * S1_P4];   // 10.2 KB
    __shared__ double wsum[4];
    __shared__ int    voteArr[16];

    const int tid = threadIdx.x;
    // channel-sibling XCD swizzle: x = XCD, q>>2 = spatial-within-XCD, q&3 = c
    const int x  = blockIdx.x & 7;
    const int q  = blockIdx.x >> 3;
    const int c  = q & 3;
    const int t  = x * 32 + (q >> 2);   // spatial tile id 0..255
    const int y0 = (t & 15) << 3;
    const int zb = ((t >> 4) & 7) << 4;
    const int b  = (t >> 7) & 1;
    const int bc = b * 4 + c;
    const int fid = (bc << 7) | (((t >> 4) & 7) << 4) | (t & 15);

    const float4* in4 = (const float4*)in;
    const int4*   tg4 = (const int4*)tgt;
    const size_t  chb = ((size_t)(b * 4)) << 19;   // channel-0 slab of batch b
    const size_t  co0 = chb + ((size_t)c << 19);   // owned channel first
    const size_t  co1 = chb + ((size_t)((c + 1) & 3) << 19);
    const size_t  co2 = chb + ((size_t)((c + 2) & 3) << 19);
    const size_t  co3 = chb + ((size_t)((c + 3) & 3) << 19);
    float4*       dp  = dst + ((size_t)bc << 19);
    const float wk = kern[13];          // all 7 taps equal
    const float bs = bias[c];

    const int col  = tid & 31;
    const int trow = tid >> 5;

    if (tid < 16) voteArr[tid] = 0;

    // ---- commit maps (input rows 0..11 <-> gy = y0+row-2) ----
    const int  gy0  = y0 + trow - 2;               // rows 0..7
    const bool lv0  = ((unsigned)gy0 < 128u);
    const int  off0 = (lv0 ? gy0 : 0) * 32 + col;
    const bool act1 = (tid < 128);                 // rows 8..11
    const int  gy1  = y0 + trow + 6;
    const bool lv1  = act1 && ((unsigned)gy1 < 128u);
    const int  off1 = (lv1 ? gy1 : 0) * 32 + col;

    // ---- s1 ragged rows {0,9} on tid<64 (primary row trow+1 is mask-free) --
    const bool  sact1 = (tid < 64);
    const int   sr  = (tid < 32) ? 0 : 9;
    const float m1  = ((unsigned)(y0 + sr - 1) < 128u) ? 1.f : 0.f;
    const int   ci1 = (sr + 1) * 32 + (tid & 31);  // input center for row sr
    const int   so1 = sr * 32 + (tid & 31);        // s1-plane store index

    const float lmask = (col == 0)  ? 0.f : 1.f;   // x=0 edge
    const float rmask = (col == 31) ? 0.f : 1.f;   // x=127 edge

    const int go4 = (y0 + trow) * 32 + col;        // owned global f4 offset

    const float4 f4z = make_float4(0.f, 0.f, 0.f, 0.f);
    float4 A00 = f4z, A01 = f4z, A02 = f4z, A03 = f4z;
    float4 A10 = f4z, A11 = f4z, A12 = f4z, A13 = f4z;
    int4   T0 = make_int4(0,0,0,0), T1 = make_int4(0,0,0,0);
    bool   ok0 = false, ok1 = false;
    float4 s_m = f4z, s_c = f4z, s_p = f4z;        // s1 chain (rows trow+1)
    float4 vH  = f4z;                              // held s2 plane (deferred)

    auto prefetch = [&](int L) {
        const bool zok = ((unsigned)L < 128u);
        ok0 = zok && lv0;
        ok1 = zok && lv1;
        if (ok0) {
            size_t o = (size_t)(L << 12) + off0;
            A00 = in4[co0 + o];
            A01 = in4[co1 + o];
            A02 = in4[co2 + o];
            A03 = in4[co3 + o];
            T0  = tg4[((size_t)b << 19) + o];
        }
        if (ok1) {
            size_t o = (size_t)(L << 12) + off1;
            A10 = in4[co0 + o];
            A11 = in4[co1 + o];
            A12 = in4[co2 + o];
            A13 = in4[co3 + o];
            T1  = tg4[((size_t)b << 19) + o];
        }
    };
    // softmax + onehot-diff + square; B0 is the OWNED channel.
    auto op_one = [&](const float4& B0, const float4& B1, const float4& B2,
                      const float4& B3, const int4& T) -> float4 {
        float4 r;
        #define OP1(K)                                                         \
        {                                                                      \
            float vc = B0.K;                                                   \
            float sm = 1.0f + __expf(B1.K - vc) + __expf(B2.K - vc)            \
                            + __expf(B3.K - vc);                               \
            float d  = __builtin_amdgcn_rcpf(sm) - ((T.K == c) ? 1.0f : 0.0f); \
            r.K = d * d;                                                       \
        }
        OP1(x) OP1(y) OP1(z) OP1(w)
        #undef OP1
        return r;
    };
    auto commit = [&](int L) {
        float4* sl = lin + SLOT4(L) * IN_P4;
        float4 v0 = f4z, v1 = f4z;
        if (ok0) v0 = op_one(A00, A01, A02, A03, T0);
        if (ok1) v1 = op_one(A10, A11, A12, A13, T1);
        sl[tid] = v0;
        if (act1) sl[256 + tid] = v1;
    };
    auto s1one = [&](const float4* pzm, const float4* pzc, const float4* pzp,
                     int ci, float ym) -> float4 {
        float4 qC = pzc[ci];
        float4 qU = pzc[ci - 32];
        float4 qD = pzc[ci + 32];
        float4 qm = pzm[ci];
        float4 qp = pzp[ci];
        float lf = __shfl_up(qC.w, 1, 64)   * lmask;
        float rt = __shfl_down(qC.x, 1, 64) * rmask;
        float4 v;
        v.x = fmaxf((qC.x + lf   + qC.y + qU.x + qD.x + qm.x + qp.x) * wk + bs, 0.f) * ym;
        v.y = fmaxf((qC.y + qC.x + qC.z + qU.y + qD.y + qm.y + qp.y) * wk + bs, 0.f) * ym;
        v.z = fmaxf((qC.z + qC.y + qC.w + qU.z + qD.z + qm.z + qp.z) * wk + bs, 0.f) * ym;
        v.w = fmaxf((qC.w + qC.z + rt   + qU.w + qD.w + qm.w + qp.w) * wk + bs, 0.f) * ym;
        return v;
    };
    auto s1_phase = [&](int z) {
        float4* o = ls1 + SLOT2(z) * S1_P4;
        float4 vnew;
        if ((unsigned)z < 128u) {
            const float4* pzm = lin + SLOT4(z - 1) * IN_P4;
            const float4* pzc = lin + SLOT4(z)     * IN_P4;
            const float4* pzp = lin + SLOT4(z + 1) * IN_P4;
            vnew = s1one(pzm, pzc, pzp, tid + 64, 1.f);   // input row trow+2
            o[tid + 32] = vnew;                           // s1 row trow+1
            if (sact1) o[so1] = s1one(pzm, pzc, pzp, ci1, m1);
        } else {
            vnew = f4z;
            o[tid + 32] = f4z;
            if (sact1) o[so1] = f4z;
        }
        s_m = s_c; s_c = s_p; s_p = vnew;
    };

    double part = 0.0;

    // ---- prologue ----
    prefetch(zb - 2); commit(zb - 2);
    prefetch(zb - 1); commit(zb - 1);
    prefetch(zb);     commit(zb);
    prefetch(zb + 1);
    __syncthreads();                        // also publishes voteArr init
    s1_phase(zb - 1);                       // s_p = s1(zb-1)

    // ---- main loop: ONE barrier per plane; deferred vote-gated store ----
    for (int L = zb + 1; L <= zb + 17; ++L) {
        commit(L);                          // softmax + LDS store (slot L&3)
        __syncthreads();                    // publishes votes for zp = L-3
        const int zp = L - 3;
        if (zp >= zb && voteArr[zp - zb] != 0)
            dp[((size_t)zp << 12) + go4] = vH;
        if (L <= zb + 16) prefetch(L + 1);
        s1_phase(L - 1);
        const int zo = L - 2;
        if (zo >= zb) {
            const float4* su = ls1 + SLOT2(zo) * S1_P4;   // written last iter
            float4 u4 = su[tid];
            float4 d4 = su[tid + 64];
            float lf = __shfl_up(s_c.w, 1, 64)   * lmask;
            float rt = __shfl_down(s_c.x, 1, 64) * rmask;
            float4 v;
            v.x = fmaxf((s_c.x + lf    + s_c.y + u4.x + d4.x + s_m.x + s_p.x) * wk + bs, 0.f);
            v.y = fmaxf((s_c.y + s_c.x + s_c.z + u4.y + d4.y + s_m.y + s_p.y) * wk + bs, 0.f);
            v.z = fmaxf((s_c.z + s_c.y + s_c.w + u4.z + d4.z + s_m.z + s_p.z) * wk + bs, 0.f);
            v.w = fmaxf((s_c.w + s_c.z + rt    + u4.w + d4.w + s_m.w + s_p.w) * wk + bs, 0.f);
            float pl = c1 * (s_c.x + s_c.y + s_c.z + s_c.w)
                     + c2 * (v.x   + v.y   + v.z   + v.w);
            part += (double)pl;
            bool nzv = (v.x != 0.f) || (v.y != 0.f) || (v.z != 0.f) || (v.w != 0.f);
            if (__any(nzv) && (tid & 63) == 0) atomicOr(&voteArr[zo - zb], 1);
            vH = v;
        }
    }

    // ---- flush last plane (zo = zb+15) ----
    __syncthreads();
    if (voteArr[15] != 0) dp[((size_t)(zb + 15) << 12) + go4] = vH;

    // ---- block reduction + mask ----
    #pragma unroll
    for (int off = 32; off > 0; off >>= 1)
        part += __shfl_down(part, off, 64);
    if ((tid & 63) == 0) wsum[tid >> 6] = part;
    __syncthreads();
    if (tid == 0) {
        int mask = 0;
        #pragma unroll
        for (int i = 0; i < 16; ++i) mask |= (voteArr[i] ? 1 : 0) << i;
        flagOut[fid] = mask;
        double tot = (wsum[0] + wsum[1] + wsum[2] + wsum[3]) * (double)weight[bc];
        accs[blockIdx.x] = tot;             // first writer: initializes slot
    }
}

// ---------------------------------------------------------------------------
// Kernel B: TWO fused erosion steps (passes 1..4). XCD-swizzled blockIdx.
// Per-plane gating: neighbor tiles' 16-bit plane masks -> block-uniform
// activity words aIn (input planes), aS1 = dilate(aIn), aS2 = dilate(aS1).
// Inactive planes skip loads, s1/s2 compute, and LDS traffic entirely.
// Stores are vote-gated per plane (same deferred scheme as fused); the
// output mask exactly describes which planes were stored.
// ---------------------------------------------------------------------------
__global__ __launch_bounds__(256, 4) void erode2_kernel(
    const float4* __restrict__ src, float4* __restrict__ dst,
    const float* __restrict__ kern, const float* __restrict__ bias,
    const float* __restrict__ weight, float c1, float c2,
    int store, double* __restrict__ accs,
    const int* __restrict__ flagIn, int* __restrict__ flagOut)
{
    __shared__ float4 lin[4 * IN_P4];   // 24.6 KB
    __shared__ float4 ls1[2 * S1_P4];   // 10.2 KB
    __shared__ double wsum[4];
    __shared__ int    sf[9];
    __shared__ int    voteArr[16];

    const int tid = threadIdx.x;
    // XCD-aware bijective swizzle (1024 blocks, 1024 % 8 == 0).
    const int bid = ((blockIdx.x & 7) << 7) | (blockIdx.x >> 3);
    const int ty = bid & 15;
    const int tz = (bid >> 4) & 7;
    const int y0 = ty << 3;
    const int zb = tz << 4;
    const int bc = bid >> 7;            // b*4 + c in [0,8)

    // ---- load 3x3 neighbor masks (sf[(dz+1)*3 + (dy+1)]) ----
    if (tid < 9) {
        int dy = tid % 3 - 1, dz = tid / 3 - 1;
        int yt = ty + dy, zt = tz + dz;
        int f = 0;
        if ((unsigned)yt < 16u && (unsigned)zt < 8u)
            f = flagIn[(bc << 7) | (zt << 4) | yt];
        sf[tid] = f;
    }
    if (tid < 16) voteArr[tid] = 0;
    __syncthreads();

    // ---- block-uniform activity words: bit i <-> plane zb-2+i, i in [0,20) --
    unsigned aInW = 0;
    #pragma unroll
    for (int i = 0; i < 20; ++i) {
        int L = zb - 2 + i;
        if ((unsigned)L < 128u) {
            int zi = (L >> 4) - tz + 1;            // 0..2
            int m  = sf[zi * 3] | sf[zi * 3 + 1] | sf[zi * 3 + 2];
            aInW |= (unsigned)((m >> (L & 15)) & 1) << i;
        }
    }
    if (aInW == 0) {                    // nothing in reach -> output all zero
        if (tid == 0) flagOut[bid] = 0;
        return;                         // uniform exit; no loads/stores
    }
    const unsigned aS1W = aInW | (aInW << 1) | (aInW >> 1);
    const unsigned aS2W = aS1W | (aS1W << 1) | (aS1W >> 1);

    const float4* sp = src + ((size_t)bc << 19);   // slab = 2^19 f4
    float4*       dp = dst + ((size_t)bc << 19);
    const float wk = kern[13];          // all 7 taps equal
    const float bs = bias[bc & 3];

    const int col  = tid & 31;
    const int trow = tid >> 5;

    // ---- commit maps (input rows 0..11 <-> gy = y0+row-2) ----
    const int  gy0  = y0 + trow - 2;               // rows 0..7
    const bool lv0  = ((unsigned)gy0 < 128u);
    const int  off0 = (lv0 ? gy0 : 0) * 32 + col;
    const bool act1 = (tid < 128);                 // rows 8..11
    const int  gy1  = y0 + trow + 6;
    const bool lv1  = act1 && ((unsigned)gy1 < 128u);
    const int  off1 = (lv1 ? gy1 : 0) * 32 + col;

    // per-thread y-tile offsets into sf (clamped; only used under lv*)
    const int yd0c = (unsigned)((gy0 >> 3) - ty + 1) < 3u ? ((gy0 >> 3) - ty + 1) : 1;
    const int yd1c = (unsigned)((gy1 >> 3) - ty + 1) < 3u ? ((gy1 >> 3) - ty + 1) : 1;

    // ---- s1 ragged rows {0,9} on tid<64 ----
    const bool  sact1 = (tid < 64);
    const int   sr  = (tid < 32) ? 0 : 9;
    const float m1  = ((unsigned)(y0 + sr - 1) < 128u) ? 1.f : 0.f;
    const int   ci1 = (sr + 1) * 32 + (tid & 31);
    const int   so1 = sr * 32 + (tid & 31);

    const float lmask = (col == 0)  ? 0.f : 1.f;
    const float rmask = (col == 31) ? 0.f : 1.f;

    const int go4 = (y0 + trow) * 32 + col;

    const float4 f4z = make_float4(0.f, 0.f, 0.f, 0.f);
    float4 pf0 = f4z, pf1 = f4z;
    float4 s_m = f4z, s_c = f4z, s_p = f4z;
    float4 vH  = f4z;

    auto prefetch = [&](int L) {
        pf0 = f4z; pf1 = f4z;
        if ((unsigned)L < 128u) {
            const int zi = (L >> 4) - tz + 1;      // 0..2
            const int sh = L & 15;
            const float4* zp = sp + ((size_t)L << 12);
            if (lv0 && ((sf[zi * 3 + yd0c] >> sh) & 1)) pf0 = zp[off0];
            if (lv1 && ((sf[zi * 3 + yd1c] >> sh) & 1)) pf1 = zp[off1];
        }
    };
    auto commit = [&](int L) {
        float4* sl = lin + SLOT4(L) * IN_P4;
        sl[tid] = pf0;
        if (act1) sl[256 + tid] = pf1;
    };
    auto s1one = [&](const float4* pzm, const float4* pzc, const float4* pzp,
                     int ci, float ym) -> float4 {
        float4 qC = pzc[ci];
        float4 qU = pzc[ci - 32];
        float4 qD = pzc[ci + 32];
        float4 qm = pzm[ci];
        float4 qp = pzp[ci];
        float lf = __shfl_up(qC.w, 1, 64)   * lmask;
        float rt = __shfl_down(qC.x, 1, 64) * rmask;
        float4 v;
        v.x = fmaxf((qC.x + lf   + qC.y + qU.x + qD.x + qm.x + qp.x) * wk + bs, 0.f) * ym;
        v.y = fmaxf((qC.y + qC.x + qC.z + qU.y + qD.y + qm.y + qp.y) * wk + bs, 0.f) * ym;
        v.z = fmaxf((qC.z + qC.y + qC.w + qU.z + qD.z + qm.z + qp.z) * wk + bs, 0.f) * ym;
        v.w = fmaxf((qC.w + qC.z + rt   + qU.w + qD.w + qm.w + qp.w) * wk + bs, 0.f) * ym;
        return v;
    };
    // s1 for plane z, gated by aS1W (consumers use the same bit)
    auto s1_phase = [&](int z) {
        float4 vnew = f4z;
        if ((unsigned)z < 128u && ((aS1W >> (z - zb + 2)) & 1)) {
            float4* o = ls1 + SLOT2(z) * S1_P4;
            const float4* pzm = lin + SLOT4(z - 1) * IN_P4;
            const float4* pzc = lin + SLOT4(z)     * IN_P4;
            const float4* pzp = lin + SLOT4(z + 1) * IN_P4;
            vnew = s1one(pzm, pzc, pzp, tid + 64, 1.f);
            o[tid + 32] = vnew;
            if (sact1) o[so1] = s1one(pzm, pzc, pzp, ci1, m1);
        }
        s_m = s_c; s_c = s_p; s_p = vnew;
    };

    double part = 0.0;

    prefetch(zb - 2); commit(zb - 2);
    prefetch(zb - 1); commit(zb - 1);
    prefetch(zb);     commit(zb);
    prefetch(zb + 1);
    __syncthreads();
    s1_phase(zb - 1);

    for (int L = zb + 1; L <= zb + 17; ++L) {
        commit(L);
        __syncthreads();                    // publishes votes for zp = L-3
        const int zp = L - 3;
        if (store && zp >= zb && voteArr[zp - zb] != 0)
            dp[((size_t)zp << 12) + go4] = vH;
        if (L <= zb + 16) prefetch(L + 1);
        s1_phase(L - 1);
        const int zo = L - 2;
        if (zo >= zb) {
            float4 v = f4z;
            if ((aS2W >> (zo - zb + 2)) & 1) {
                float4 u4 = f4z, d4 = f4z;
                if ((aS1W >> (zo - zb + 2)) & 1) {
                    const float4* su = ls1 + SLOT2(zo) * S1_P4;
                    u4 = su[tid];
                    d4 = su[tid + 64];
                }
                float lf = __shfl_up(s_c.w, 1, 64)   * lmask;
                float rt = __shfl_down(s_c.x, 1, 64) * rmask;
                v.x = fmaxf((s_c.x + lf    + s_c.y + u4.x + d4.x + s_m.x + s_p.x) * wk + bs, 0.f);
                v.y = fmaxf((s_c.y + s_c.x + s_c.z + u4.y + d4.y + s_m.y + s_p.y) * wk + bs, 0.f);
                v.z = fmaxf((s_c.z + s_c.y + s_c.w + u4.z + d4.z + s_m.z + s_p.z) * wk + bs, 0.f);
                v.w = fmaxf((s_c.w + s_c.z + rt    + u4.w + d4.w + s_m.w + s_p.w) * wk + bs, 0.f);
                float pl = c1 * (s_c.x + s_c.y + s_c.z + s_c.w)
                         + c2 * (v.x   + v.y   + v.z   + v.w);
                part += (double)pl;
                bool nzv = (v.x != 0.f) || (v.y != 0.f) || (v.z != 0.f) || (v.w != 0.f);
                if (__any(nzv) && (tid & 63) == 0) atomicOr(&voteArr[zo - zb], 1);
            }
            vH = v;
        }
    }

    __syncthreads();
    if (store && voteArr[15] != 0) dp[((size_t)(zb + 15) << 12) + go4] = vH;

    #pragma unroll
    for (int off = 32; off > 0; off >>= 1)
        part += __shfl_down(part, off, 64);
    if ((tid & 63) == 0) wsum[tid >> 6] = part;
    __syncthreads();
    if (tid == 0) {
        int mask = 0;
        #pragma unroll
        for (int i = 0; i < 16; ++i) mask |= (voteArr[i] ? 1 : 0) << i;
        flagOut[bid] = mask;
        double tot = (wsum[0] + wsum[1] + wsum[2] + wsum[3]) * (double)weight[bc];
        atomicAdd(&accs[bid], tot);         // slot initialized by fused pass 0
    }
}

// Reduce the NACC per-block accumulators -> scalar mean.
__global__ __launch_bounds__(1024) void finalize_kernel(
    const double* __restrict__ accs, float* __restrict__ out)
{
    __shared__ double wsum[16];
    double v = accs[threadIdx.x];
    #pragma unroll
    for (int off = 32; off > 0; off >>= 1)
        v += __shfl_down(v, off, 64);
    int lane = threadIdx.x & 63;
    int wid  = threadIdx.x >> 6;
    if (lane == 0) wsum[wid] = v;
    __syncthreads();
    if (threadIdx.x == 0) {
        double tot = 0.0;
        #pragma unroll
        for (int i = 0; i < 16; ++i) tot += wsum[i];
        out[0] = (float)(tot / (double)NTOT);
    }
}

extern "C" void kernel_launch(void* const* d_in, const int* in_sizes, int n_in,
                              void* d_out, int out_size, void* d_ws, size_t ws_size,
                              hipStream_t stream) {
    const float* in     = (const float*)d_in[0];
    const int*   tgt    = (const int*)d_in[1];
    const float* weight = (const float*)d_in[2];
    const float* kern   = (const float*)d_in[3];
    const float* bias   = (const float*)d_in[4];
    float* out = (float*)d_out;

    char* ws = (char*)d_ws;
    float*  buf0   = (float*)ws;
    float*  buf1   = (float*)(ws + (size_t)NTOT * sizeof(float));
    double* accs   = (double*)(ws + (size_t)NTOT * 2 * sizeof(float));
    int*    flagsA = (int*)(ws + (size_t)NTOT * 2 * sizeof(float) + NACC * sizeof(double));
    int*    flagsB = flagsA + NACC;

    // 1) fused softmax+square+double-erosion pass 0: in -> buf0
    //    (inits accs; writes per-plane masks to flagsA; stores only
    //     nonzero planes)
    fused_sm_erode2_kernel<<<1024, 256, 0, stream>>>(
        in, tgt, (float4*)buf0, kern, bias, weight, 1.0f, 4.0f, accs, flagsA);

    // 2) 4 more fused double-erosion passes with per-plane skipping;
    //    masks ping-pong; last pass skips stores entirely
    float* cur = buf0;
    float* nxt = buf1;
    int*   fIn = flagsA;
    int*   fOut = flagsB;
    for (int p = 1; p < 5; ++p) {
        float c1 = (float)((2 * p + 1) * (2 * p + 1));
        float c2 = (float)((2 * p + 2) * (2 * p + 2));
        int   store = (p < 4) ? 1 : 0;
        erode2_kernel<<<1024, 256, 0, stream>>>(
            (const float4*)cur, (float4*)nxt, kern, bias, weight, c1, c2,
            store, accs, fIn, fOut);
        float* tb = cur; cur = nxt; nxt = tb;
        int*   tf = fIn; fIn = fOut; fOut = tf;
    }

    // 3) reduce + mean
    finalize_kernel<<<1, 1024, 0, stream>>>(accs, out);
}

// Round 9
// 153.907 us; speedup vs baseline: 1.8647x; 1.0093x over previous
//
#include <hip/hip_runtime.h>

// Problem constants (match reference)
#define DHW   (128*128*128)        // 2^21
#define CDHW  (4*DHW)              // 2^23
#define NTOT  (2*CDHW)             // 2^24 = 16,777,216
#define NACC  1024                 // one accumulator slot per erode block

// fused (erode2) tiling: full x-row (32 f4), 8 owned y-rows, 16 owned z.
#define ROW4     32
#define IN_ROWS  12                // 8 + 2*2 y-halo
#define S1_ROWS  10                // 8 + 2*1
#define IN_P4    (IN_ROWS*ROW4)    // 384 f4 / input plane
#define S1_P4    (S1_ROWS*ROW4)    // 320 f4 / s1 plane
#define SLOT4(z) (((z)+8)&3)       // 4-slot ring
#define SLOT2(z) (((z)+8)&1)       // 2-slot ring

// Flag word per tile: 16-bit mask, bit (z-zb) = plane z has a nonzero.
// fid = (bc<<7) | (tz<<4) | ty.

// ---------------------------------------------------------------------------
// Fused pass 0 (R7, proven): softmax + (p-onehot)^2 during staging, then TWO
// erosion steps; per-plane vote-gated stores + 16-bit plane-mask flags.
// ---------------------------------------------------------------------------
__global__ __launch_bounds__(256, 4) void fused_sm_erode2_kernel(
    const float* __restrict__ in, const int* __restrict__ tgt,
    float4* __restrict__ dst,
    const float* __restrict__ kern, const float* __restrict__ bias,
    const float* __restrict__ weight, float c1, float c2,
    double* __restrict__ accs, int* __restrict__ flagOut)
{
    __shared__ float4 lin[4 * IN_P4];
    __shared__ float4 ls1[2 * S1_P4];
    __shared__ double wsum[4];
    __shared__ int    voteArr[16];

    const int tid = threadIdx.x;
    const int x  = blockIdx.x & 7;
    const int q  = blockIdx.x >> 3;
    const int c  = q & 3;
    const int t  = x * 32 + (q >> 2);
    const int y0 = (t & 15) << 3;
    const int zb = ((t >> 4) & 7) << 4;
    const int b  = (t >> 7) & 1;
    const int bc = b * 4 + c;
    const int fid = (bc << 7) | (((t >> 4) & 7) << 4) | (t & 15);

    const float4* in4 = (const float4*)in;
    const int4*   tg4 = (const int4*)tgt;
    const size_t  chb = ((size_t)(b * 4)) << 19;
    const size_t  co0 = chb + ((size_t)c << 19);
    const size_t  co1 = chb + ((size_t)((c + 1) & 3) << 19);
    const size_t  co2 = chb + ((size_t)((c + 2) & 3) << 19);
    const size_t  co3 = chb + ((size_t)((c + 3) & 3) << 19);
    float4*       dp  = dst + ((size_t)bc << 19);
    const float wk = kern[13];
    const float bs = bias[c];

    const int col  = tid & 31;
    const int trow = tid >> 5;

    if (tid < 16) voteArr[tid] = 0;

    const int  gy0  = y0 + trow - 2;
    const bool lv0  = ((unsigned)gy0 < 128u);
    const int  off0 = (lv0 ? gy0 : 0) * 32 + col;
    const bool act1 = (tid < 128);
    const int  gy1  = y0 + trow + 6;
    const bool lv1  = act1 && ((unsigned)gy1 < 128u);
    const int  off1 = (lv1 ? gy1 : 0) * 32 + col;

    const bool  sact1 = (tid < 64);
    const int   sr  = (tid < 32) ? 0 : 9;
    const float m1  = ((unsigned)(y0 + sr - 1) < 128u) ? 1.f : 0.f;
    const int   ci1 = (sr + 1) * 32 + (tid & 31);
    const int   so1 = sr * 32 + (tid & 31);

    const float lmask = (col == 0)  ? 0.f : 1.f;
    const float rmask = (col == 31) ? 0.f : 1.f;

    const int go4 = (y0 + trow) * 32 + col;

    const float4 f4z = make_float4(0.f, 0.f, 0.f, 0.f);
    float4 A00 = f4z, A01 = f4z, A02 = f4z, A03 = f4z;
    float4 A10 = f4z, A11 = f4z, A12 = f4z, A13 = f4z;
    int4   T0 = make_int4(0,0,0,0), T1 = make_int4(0,0,0,0);
    bool   ok0 = false, ok1 = false;
    float4 s_m = f4z, s_c = f4z, s_p = f4z;
    float4 vH  = f4z;

    auto prefetch = [&](int L) {
        const bool zok = ((unsigned)L < 128u);
        ok0 = zok && lv0;
        ok1 = zok && lv1;
        if (ok0) {
            size_t o = (size_t)(L << 12) + off0;
            A00 = in4[co0 + o];
            A01 = in4[co1 + o];
            A02 = in4[co2 + o];
            A03 = in4[co3 + o];
            T0  = tg4[((size_t)b << 19) + o];
        }
        if (ok1) {
            size_t o = (size_t)(L << 12) + off1;
            A10 = in4[co0 + o];
            A11 = in4[co1 + o];
            A12 = in4[co2 + o];
            A13 = in4[co3 + o];
            T1  = tg4[((size_t)b << 19) + o];
        }
    };
    auto op_one = [&](const float4& B0, const float4& B1, const float4& B2,
                      const float4& B3, const int4& T) -> float4 {
        float4 r;
        #define OP1(K)                                                         \
        {                                                                      \
            float vc = B0.K;                                                   \
            float sm = 1.0f + __expf(B1.K - vc) + __expf(B2.K - vc)            \
                            + __expf(B3.K - vc);                               \
            float d  = __builtin_amdgcn_rcpf(sm) - ((T.K == c) ? 1.0f : 0.0f); \
            r.K = d * d;                                                       \
        }
        OP1(x) OP1(y) OP1(z) OP1(w)
        #undef OP1
        return r;
    };
    auto commit = [&](int L) {
        float4* sl = lin + SLOT4(L) * IN_P4;
        float4 v0 = f4z, v1 = f4z;
        if (ok0) v0 = op_one(A00, A01, A02, A03, T0);
        if (ok1) v1 = op_one(A10, A11, A12, A13, T1);
        sl[tid] = v0;
        if (act1) sl[256 + tid] = v1;
    };
    auto s1one = [&](const float4* pzm, const float4* pzc, const float4* pzp,
                     int ci, float ym) -> float4 {
        float4 qC = pzc[ci];
        float4 qU = pzc[ci - 32];
        float4 qD = pzc[ci + 32];
        float4 qm = pzm[ci];
        float4 qp = pzp[ci];
        float lf = __shfl_up(qC.w, 1, 64)   * lmask;
        float rt = __shfl_down(qC.x, 1, 64) * rmask;
        float4 v;
        v.x = fmaxf((qC.x + lf   + qC.y + qU.x + qD.x + qm.x + qp.x) * wk + bs, 0.f) * ym;
        v.y = fmaxf((qC.y + qC.x + qC.z + qU.y + qD.y + qm.y + qp.y) * wk + bs, 0.f) * ym;
        v.z = fmaxf((qC.z + qC.y + qC.w + qU.z + qD.z + qm.z + qp.z) * wk + bs, 0.f) * ym;
        v.w = fmaxf((qC.w + qC.z + rt   + qU.w + qD.w + qm.w + qp.w) * wk + bs, 0.f) * ym;
        return v;
    };
    auto s1_phase = [&](int z) {
        float4* o = ls1 + SLOT2(z) * S1_P4;
        float4 vnew;
        if ((unsigned)z < 128u) {
            const float4* pzm = lin + SLOT4(z - 1) * IN_P4;
            const float4* pzc = lin + SLOT4(z)     * IN_P4;
            const float4* pzp = lin + SLOT4(z + 1) * IN_P4;
            vnew = s1one(pzm, pzc, pzp, tid + 64, 1.f);
            o[tid + 32] = vnew;
            if (sact1) o[so1] = s1one(pzm, pzc, pzp, ci1, m1);
        } else {
            vnew = f4z;
            o[tid + 32] = f4z;
            if (sact1) o[so1] = f4z;
        }
        s_m = s_c; s_c = s_p; s_p = vnew;
    };

    double part = 0.0;

    prefetch(zb - 2); commit(zb - 2);
    prefetch(zb - 1); commit(zb - 1);
    prefetch(zb);     commit(zb);
    prefetch(zb + 1);
    __syncthreads();
    s1_phase(zb - 1);

    for (int L = zb + 1; L <= zb + 17; ++L) {
        commit(L);
        __syncthreads();                    // publishes votes for zp = L-3
        const int zp = L - 3;
        if (zp >= zb && voteArr[zp - zb] != 0)
            dp[((size_t)zp << 12) + go4] = vH;
        if (L <= zb + 16) prefetch(L + 1);
        s1_phase(L - 1);
        const int zo = L - 2;
        if (zo >= zb) {
            const float4* su = ls1 + SLOT2(zo) * S1_P4;
            float4 u4 = su[tid];
            float4 d4 = su[tid + 64];
            float lf = __shfl_up(s_c.w, 1, 64)   * lmask;
            float rt = __shfl_down(s_c.x, 1, 64) * rmask;
            float4 v;
            v.x = fmaxf((s_c.x + lf    + s_c.y + u4.x + d4.x + s_m.x + s_p.x) * wk + bs, 0.f);
            v.y = fmaxf((s_c.y + s_c.x + s_c.z + u4.y + d4.y + s_m.y + s_p.y) * wk + bs, 0.f);
            v.z = fmaxf((s_c.z + s_c.y + s_c.w + u4.z + d4.z + s_m.z + s_p.z) * wk + bs, 0.f);
            v.w = fmaxf((s_c.w + s_c.z + rt    + u4.w + d4.w + s_m.w + s_p.w) * wk + bs, 0.f);
            float pl = c1 * (s_c.x + s_c.y + s_c.z + s_c.w)
                     + c2 * (v.x   + v.y   + v.z   + v.w);
            part += (double)pl;
            bool nzv = (v.x != 0.f) || (v.y != 0.f) || (v.z != 0.f) || (v.w != 0.f);
            if (__any(nzv) && (tid & 63) == 0) atomicOr(&voteArr[zo - zb], 1);
            vH = v;
        }
    }

    __syncthreads();
    if (voteArr[15] != 0) dp[((size_t)(zb + 15) << 12) + go4] = vH;

    #pragma unroll
    for (int off = 32; off > 0; off >>= 1)
        part += __shfl_down(part, off, 64);
    if ((tid & 63) == 0) wsum[tid >> 6] = part;
    __syncthreads();
    if (tid == 0) {
        int mask = 0;
        #pragma unroll
        for (int i = 0; i < 16; ++i) mask |= (voteArr[i] ? 1 : 0) << i;
        flagOut[fid] = mask;
        double tot = (wsum[0] + wsum[1] + wsum[2] + wsum[3]) * (double)weight[bc];
        accs[blockIdx.x] = tot;
    }
}

// ---------------------------------------------------------------------------
// erode4: FOUR fused erosion steps per dispatch. Stage k primary row lives in
// a 3-deep register z-chain at gy=y0+trow; u/d rows via 2-slot LDS ring per
// stage; ragged halo rows (s1:{0,1,2,11,12,13}, s2:{0,1,10,11}, s3:{0,9})
// handled by wave-aligned groups keeping their own chains (recompute the
// stage-below center locally). Per-plane activity words a1..a4 (dilations of
// the input masks) gate everything. Vote-gated deferred stores. All
// cross-block dataflow at kernel boundaries (no coop races).
// ---------------------------------------------------------------------------
#define E4_INP4  512   // 16 rows * 32
#define E4_S1P4  448   // 14 rows * 32
#define E4_S2P4  384   // 12 rows * 32
#define E4_S3P4  320   // 10 rows * 32

__global__ __launch_bounds__(256, 2) void erode4_kernel(
    const float4* __restrict__ src, float4* __restrict__ dst,
    const float* __restrict__ kern, const float* __restrict__ bias,
    const float* __restrict__ weight,
    float c1, float c2, float c3, float c4,
    int store, double* __restrict__ accs,
    const int* __restrict__ flagIn, int* __restrict__ flagOut)
{
    __shared__ float4 lin[4 * E4_INP4];   // 32 KB
    __shared__ float4 ls1[2 * E4_S1P4];   // 14 KB
    __shared__ float4 ls2[2 * E4_S2P4];   // 12 KB
    __shared__ float4 ls3[2 * E4_S3P4];   // 10 KB
    __shared__ double wsum[4];
    __shared__ int    sf[9];
    __shared__ int    voteArr[16];

    const int tid = threadIdx.x;
    const int bid = ((blockIdx.x & 7) << 7) | (blockIdx.x >> 3);
    const int ty = bid & 15;
    const int tz = (bid >> 4) & 7;
    const int y0 = ty << 3;
    const int zb = tz << 4;
    const int bc = bid >> 7;

    if (tid < 9) {
        int dy = tid % 3 - 1, dz = tid / 3 - 1;
        int yt = ty + dy, zt = tz + dz;
        int f = 0;
        if ((unsigned)yt < 16u && (unsigned)zt < 8u)
            f = flagIn[(bc << 7) | (zt << 4) | yt];
        sf[tid] = f;
    }
    if (tid < 16) voteArr[tid] = 0;
    __syncthreads();

    // activity words: bit i <-> plane zb-4+i, i in [0,24)
    unsigned aIn = 0, zc = 0;
    #pragma unroll
    for (int i = 0; i < 24; ++i) {
        int L = zb - 4 + i;
        if ((unsigned)L < 128u) {
            zc |= 1u << i;
            int zi = (L >> 4) - tz + 1;
            int m = sf[zi * 3] | sf[zi * 3 + 1] | sf[zi * 3 + 2];
            aIn |= (unsigned)((m >> (L & 15)) & 1) << i;
        }
    }
    if (aIn == 0) { if (tid == 0) flagOut[bid] = 0; return; }

    // dilate per stage; clamp to z in [0,128) and computable ranges
    const unsigned a1 = (aIn | aIn << 1 | aIn >> 1) & zc & 0x7FFFFEu; // ib 1..22
    const unsigned a2 = (a1  | a1  << 1 | a1  >> 1) & zc & 0x3FFFFCu; // ib 2..21
    const unsigned a3 = (a2  | a2  << 1 | a2  >> 1) & zc & 0x1FFFF8u; // ib 3..20
    const unsigned a4 = (a3  | a3  << 1 | a3  >> 1) & zc & 0x0FFFF0u; // ib 4..19

    const float4* sp = src + ((size_t)bc << 19);
    float4*       dp = dst + ((size_t)bc << 19);
    const float wk = kern[13];
    const float bs = bias[bc & 3];

    const int col  = tid & 31;
    const int trow = tid >> 5;
    const int g    = trow;              // 32-thread group id

    // staging: rows trow and trow+8 of the 16-row window; gy = y0-4+row
    const int  gy0 = y0 - 4 + trow;
    const int  gy1 = y0 + 4 + trow;
    const bool lv0 = ((unsigned)gy0 < 128u);
    const bool lv1 = ((unsigned)gy1 < 128u);
    const int  off0 = (lv0 ? gy0 : 0) * 32 + col;
    const int  off1 = (lv1 ? gy1 : 0) * 32 + col;
    const int  yd0 = ((unsigned)((gy0 >> 3) - ty + 1) < 3u) ? ((gy0 >> 3) - ty + 1) : 1;
    const int  yd1 = ((unsigned)((gy1 >> 3) - ty + 1) < 3u) ? ((gy1 >> 3) - ty + 1) : 1;

    // ragged row constants
    const int   r1  = (g < 3) ? g : g + 8;             // s1 rows {0,1,2,11,12,13}
    const float ym1 = ((unsigned)(y0 - 3 + r1) < 128u) ? 1.f : 0.f;
    const int   ci1 = (r1 + 1) * 32 + col;
    const int   R2  = (g < 2) ? g : g + 8;             // s2 rows {0,1,10,11}
    const float ym2 = ((unsigned)(y0 - 2 + R2) < 128u) ? 1.f : 0.f;
    const int   ci2 = (R2 + 2) * 32 + col;
    const int   S3  = g * 9;                           // s3 rows {0,9}
    const float ym3 = ((unsigned)(y0 - 1 + S3) < 128u) ? 1.f : 0.f;
    const int   ci3 = (S3 + 3) * 32 + col;

    const float lmask = (col == 0)  ? 0.f : 1.f;
    const float rmask = (col == 31) ? 0.f : 1.f;
    const int   go4  = (y0 + trow) * 32 + col;

    const float4 f4z = make_float4(0.f, 0.f, 0.f, 0.f);
    float4 pf0 = f4z, pf1 = f4z;
    // register z-chains
    float4 p1m=f4z,p1c=f4z,p1p=f4z;   // primary s1 @ gy=y0+trow
    float4 p2m=f4z,p2c=f4z,p2p=f4z;   // primary s2
    float4 p3m=f4z,p3c=f4z,p3p=f4z;   // primary s3
    float4 o1m=f4z,o1c=f4z,o1p=f4z;   // s2-ragged own s1 @ gy2 (tid<128)
    float4 q1m=f4z,q1c=f4z,q1p=f4z;   // s3-ragged own s1 @ gy3 (tid<64)
    float4 q2m=f4z,q2c=f4z,q2p=f4z;   // s3-ragged own s2 @ gy3 (tid<64)
    float4 vH = f4z;
    double part = 0.0;

    auto st7 = [&](const float4& zm, const float4& cc, const float4& zp,
                   const float4& u, const float4& d, float ym) -> float4 {
        float lf = __shfl_up(cc.w, 1, 64)   * lmask;
        float rt = __shfl_down(cc.x, 1, 64) * rmask;
        float4 v;
        v.x = fmaxf((cc.x + lf   + cc.y + u.x + d.x + zm.x + zp.x) * wk + bs, 0.f) * ym;
        v.y = fmaxf((cc.y + cc.x + cc.z + u.y + d.y + zm.y + zp.y) * wk + bs, 0.f) * ym;
        v.z = fmaxf((cc.z + cc.y + cc.w + u.z + d.z + zm.z + zp.z) * wk + bs, 0.f) * ym;
        v.w = fmaxf((cc.w + cc.z + rt   + u.w + d.w + zm.w + zp.w) * wk + bs, 0.f) * ym;
        return v;
    };
    auto s1at = [&](int z, int ci, float ym) -> float4 {
        const float4* pzm = lin + SLOT4(z - 1) * E4_INP4;
        const float4* pzc = lin + SLOT4(z)     * E4_INP4;
        const float4* pzp = lin + SLOT4(z + 1) * E4_INP4;
        return st7(pzm[ci], pzc[ci], pzp[ci], pzc[ci - 32], pzc[ci + 32], ym);
    };
    auto prefetch = [&](int L) {
        pf0 = f4z; pf1 = f4z;
        if (L >= zb - 4 && L <= zb + 19 && (unsigned)L < 128u) {
            const int zi = (L >> 4) - tz + 1;
            const int sh = L & 15;
            const float4* zp = sp + ((size_t)L << 12);
            if (lv0 && ((sf[zi * 3 + yd0] >> sh) & 1)) pf0 = zp[off0];
            if (lv1 && ((sf[zi * 3 + yd1] >> sh) & 1)) pf1 = zp[off1];
        }
    };
    auto commit = [&](int L) {
        float4* sl = lin + SLOT4(L) * E4_INP4;
        sl[trow * 32 + col]       = pf0;
        sl[(trow + 8) * 32 + col] = pf1;
    };

    prefetch(zb - 4);
    for (int L = zb - 4; L <= zb + 19; ++L) {
        commit(L);
        __syncthreads();                    // publishes votes for zs = L-5
        const int zs = L - 5;
        if (store && zs >= zb && voteArr[zs - zb] != 0)
            dp[((size_t)zs << 12) + go4] = vH;
        if (L < zb + 19) prefetch(L + 1);

        // ---- s1(z = L-1) ----
        {
            const int z = L - 1, ib = z - (zb - 4);
            float4 vp = f4z, vo = f4z, vq = f4z;
            if ((unsigned)ib < 24u && ((a1 >> ib) & 1)) {
                vp = s1at(z, (trow + 4) * 32 + col, 1.f);
                float4* o = ls1 + SLOT2(z) * E4_S1P4;
                if (tid < 192) o[r1 * 32 + col] = s1at(z, ci1, ym1);
                if (tid < 128) vo = s1at(z, ci2, ym2);
                if (tid < 64)  vq = s1at(z, ci3, ym3);
                o[(trow + 3) * 32 + col] = vp;
                if (z >= zb && z <= zb + 15)
                    part += (double)(c1 * (vp.x + vp.y + vp.z + vp.w));
            }
            p1m = p1c; p1c = p1p; p1p = vp;
            o1m = o1c; o1c = o1p; o1p = vo;
            q1m = q1c; q1c = q1p; q1p = vq;
        }
        // ---- s2(z = L-2) ----
        {
            const int z = L - 2, ib = z - (zb - 4);
            float4 vp = f4z, vq = f4z;
            if ((unsigned)ib < 24u && ((a2 >> ib) & 1)) {
                const bool l1 = ((a1 >> ib) & 1);
                const float4* s1p_ = ls1 + SLOT2(z) * E4_S1P4;
                float4 u = l1 ? s1p_[(trow + 2) * 32 + col] : f4z;
                float4 d = l1 ? s1p_[(trow + 4) * 32 + col] : f4z;
                vp = st7(p1m, p1c, p1p, u, d, 1.f);
                float4* o = ls2 + SLOT2(z) * E4_S2P4;
                if (tid < 128) {
                    float4 u2 = l1 ? s1p_[R2 * 32 + col]       : f4z;
                    float4 d2 = l1 ? s1p_[(R2 + 2) * 32 + col] : f4z;
                    o[R2 * 32 + col] = st7(o1m, o1c, o1p, u2, d2, ym2);
                }
                if (tid < 64) {
                    float4 u3 = l1 ? s1p_[(S3 + 1) * 32 + col] : f4z;
                    float4 d3 = l1 ? s1p_[(S3 + 3) * 32 + col] : f4z;
                    vq = st7(q1m, q1c, q1p, u3, d3, ym3);
                }
                o[(trow + 2) * 32 + col] = vp;
                if (z >= zb && z <= zb + 15)
                    part += (double)(c2 * (vp.x + vp.y + vp.z + vp.w));
            }
            p2m = p2c; p2c = p2p; p2p = vp;
            q2m = q2c; q2c = q2p; q2p = vq;
        }
        // ---- s3(z = L-3) ----
        {
            const int z = L - 3, ib = z - (zb - 4);
            float4 vp = f4z;
            if ((unsigned)ib < 24u && ((a3 >> ib) & 1)) {
                const bool l2 = ((a2 >> ib) & 1);
                const float4* s2p_ = ls2 + SLOT2(z) * E4_S2P4;
                float4 u = l2 ? s2p_[(trow + 1) * 32 + col] : f4z;
                float4 d = l2 ? s2p_[(trow + 3) * 32 + col] : f4z;
                vp = st7(p2m, p2c, p2p, u, d, 1.f);
                float4* o = ls3 + SLOT2(z) * E4_S3P4;
                if (tid < 64) {
                    float4 u3 = l2 ? s2p_[S3 * 32 + col]       : f4z;
                    float4 d3 = l2 ? s2p_[(S3 + 2) * 32 + col] : f4z;
                    o[S3 * 32 + col] = st7(q2m, q2c, q2p, u3, d3, ym3);
                }
                o[(trow + 1) * 32 + col] = vp;
                if (z >= zb && z <= zb + 15)
                    part += (double)(c3 * (vp.x + vp.y + vp.z + vp.w));
            }
            p3m = p3c; p3c = p3p; p3p = vp;
        }
        // ---- s4(z = L-4) : owned output ----
        {
            const int z = L - 4, ib = z - (zb - 4);
            float4 v = f4z;
            if ((unsigned)ib < 24u && ((a4 >> ib) & 1)) {
                const bool l3 = ((a3 >> ib) & 1);
                const float4* s3p_ = ls3 + SLOT2(z) * E4_S3P4;
                float4 u = l3 ? s3p_[trow * 32 + col]       : f4z;
                float4 d = l3 ? s3p_[(trow + 2) * 32 + col] : f4z;
                v = st7(p3m, p3c, p3p, u, d, 1.f);
                part += (double)(c4 * (v.x + v.y + v.z + v.w));
                bool nzv = (v.x != 0.f) || (v.y != 0.f) || (v.z != 0.f) || (v.w != 0.f);
                if (__any(nzv) && (tid & 63) == 0) atomicOr(&voteArr[z - zb], 1);
            }
            vH = v;
        }
    }

    __syncthreads();
    if (store && voteArr[15] != 0) dp[((size_t)(zb + 15) << 12) + go4] = vH;

    #pragma unroll
    for (int off = 32; off > 0; off >>= 1)
        part += __shfl_down(part, off, 64);
    if ((tid & 63) == 0) wsum[tid >> 6] = part;
    __syncthreads();
    if (tid == 0) {
        int mask = 0;
        #pragma unroll
        for (int i = 0; i < 16; ++i) mask |= (voteArr[i] ? 1 : 0) << i;
        flagOut[bid] = mask;
        double tot = (wsum[0] + wsum[1] + wsum[2] + wsum[3]) * (double)weight[bc];
        atomicAdd(&accs[bid], tot);
    }
}

// Reduce the NACC per-block accumulators -> scalar mean.
__global__ __launch_bounds__(1024) void finalize_kernel(
    const double* __restrict__ accs, float* __restrict__ out)
{
    __shared__ double wsum[16];
    double v = accs[threadIdx.x];
    #pragma unroll
    for (int off = 32; off > 0; off >>= 1)
        v += __shfl_down(v, off, 64);
    int lane = threadIdx.x & 63;
    int wid  = threadIdx.x >> 6;
    if (lane == 0) wsum[wid] = v;
    __syncthreads();
    if (threadIdx.x == 0) {
        double tot = 0.0;
        #pragma unroll
        for (int i = 0; i < 16; ++i) tot += wsum[i];
        out[0] = (float)(tot / (double)NTOT);
    }
}

extern "C" void kernel_launch(void* const* d_in, const int* in_sizes, int n_in,
                              void* d_out, int out_size, void* d_ws, size_t ws_size,
                              hipStream_t stream) {
    const float* in     = (const float*)d_in[0];
    const int*   tgt    = (const int*)d_in[1];
    const float* weight = (const float*)d_in[2];
    const float* kern   = (const float*)d_in[3];
    const float* bias   = (const float*)d_in[4];
    float* out = (float*)d_out;

    char* ws = (char*)d_ws;
    float*  buf0   = (float*)ws;
    float*  buf1   = (float*)(ws + (size_t)NTOT * sizeof(float));
    double* accs   = (double*)(ws + (size_t)NTOT * 2 * sizeof(float));
    int*    flagsA = (int*)(ws + (size_t)NTOT * 2 * sizeof(float) + NACC * sizeof(double));
    int*    flagsB = flagsA + NACC;

    // 1) fused softmax+square+erode^2 (steps 1-2): in -> buf0, masks -> flagsA
    fused_sm_erode2_kernel<<<1024, 256, 0, stream>>>(
        in, tgt, (float4*)buf0, kern, bias, weight, 1.0f, 4.0f, accs, flagsA);

    // 2) erode^4 (steps 3-6): buf0 -> buf1, masks flagsA -> flagsB
    erode4_kernel<<<1024, 256, 0, stream>>>(
        (const float4*)buf0, (float4*)buf1, kern, bias, weight,
        9.0f, 16.0f, 25.0f, 36.0f, 1, accs, flagsA, flagsB);

    // 3) erode^4 (steps 7-10): buf1, no store
    erode4_kernel<<<1024, 256, 0, stream>>>(
        (const float4*)buf1, (float4*)buf0, kern, bias, weight,
        49.0f, 64.0f, 81.0f, 100.0f, 0, accs, flagsB, flagsA);

    // 4) reduce + mean
    finalize_kernel<<<1, 1024, 0, stream>>>(accs, out);
}

// Round 10
// 150.519 us; speedup vs baseline: 1.9066x; 1.0225x over previous
//
#include <hip/hip_runtime.h>

// Problem constants (match reference)
#define DHW   (128*128*128)        // 2^21
#define CDHW  (4*DHW)              // 2^23
#define NTOT  (2*CDHW)             // 2^24 = 16,777,216
#define NACC  1024                 // one accumulator slot per erode block

// fused (erode2) tiling: full x-row (32 f4), 8 owned y-rows, 16 owned z.
#define ROW4     32
#define IN_ROWS  12                // 8 + 2*2 y-halo
#define S1_ROWS  10                // 8 + 2*1
#define IN_P4    (IN_ROWS*ROW4)    // 384 f4 / input plane
#define S1_P4    (S1_ROWS*ROW4)    // 320 f4 / s1 plane
#define SLOT4(z) (((z)+8)&3)       // 4-slot ring
#define SLOT2(z) (((z)+8)&1)       // 2-slot ring

// Flag word per tile: 16-bit mask, bit (z-zb) = plane z has a nonzero.
// fid = (bc<<7) | (tz<<4) | ty.

// ---------------------------------------------------------------------------
// Fused pass 0 (R7/R9, proven): softmax + (p-onehot)^2 during staging, then
// TWO erosion steps; per-plane vote-gated stores + 16-bit plane-mask flags.
// ---------------------------------------------------------------------------
__global__ __launch_bounds__(256, 4) void fused_sm_erode2_kernel(
    const float* __restrict__ in, const int* __restrict__ tgt,
    float4* __restrict__ dst,
    const float* __restrict__ kern, const float* __restrict__ bias,
    const float* __restrict__ weight, float c1, float c2,
    double* __restrict__ accs, int* __restrict__ flagOut)
{
    __shared__ float4 lin[4 * IN_P4];
    __shared__ float4 ls1[2 * S1_P4];
    __shared__ double wsum[4];
    __shared__ int    voteArr[16];

    const int tid = threadIdx.x;
    const int x  = blockIdx.x & 7;
    const int q  = blockIdx.x >> 3;
    const int c  = q & 3;
    const int t  = x * 32 + (q >> 2);
    const int y0 = (t & 15) << 3;
    const int zb = ((t >> 4) & 7) << 4;
    const int b  = (t >> 7) & 1;
    const int bc = b * 4 + c;
    const int fid = (bc << 7) | (((t >> 4) & 7) << 4) | (t & 15);

    const float4* in4 = (const float4*)in;
    const int4*   tg4 = (const int4*)tgt;
    const size_t  chb = ((size_t)(b * 4)) << 19;
    const size_t  co0 = chb + ((size_t)c << 19);
    const size_t  co1 = chb + ((size_t)((c + 1) & 3) << 19);
    const size_t  co2 = chb + ((size_t)((c + 2) & 3) << 19);
    const size_t  co3 = chb + ((size_t)((c + 3) & 3) << 19);
    float4*       dp  = dst + ((size_t)bc << 19);
    const float wk = kern[13];
    const float bs = bias[c];

    const int col  = tid & 31;
    const int trow = tid >> 5;

    if (tid < 16) voteArr[tid] = 0;

    const int  gy0  = y0 + trow - 2;
    const bool lv0  = ((unsigned)gy0 < 128u);
    const int  off0 = (lv0 ? gy0 : 0) * 32 + col;
    const bool act1 = (tid < 128);
    const int  gy1  = y0 + trow + 6;
    const bool lv1  = act1 && ((unsigned)gy1 < 128u);
    const int  off1 = (lv1 ? gy1 : 0) * 32 + col;

    const bool  sact1 = (tid < 64);
    const int   sr  = (tid < 32) ? 0 : 9;
    const float m1  = ((unsigned)(y0 + sr - 1) < 128u) ? 1.f : 0.f;
    const int   ci1 = (sr + 1) * 32 + (tid & 31);
    const int   so1 = sr * 32 + (tid & 31);

    const float lmask = (col == 0)  ? 0.f : 1.f;
    const float rmask = (col == 31) ? 0.f : 1.f;

    const int go4 = (y0 + trow) * 32 + col;

    const float4 f4z = make_float4(0.f, 0.f, 0.f, 0.f);
    float4 A00 = f4z, A01 = f4z, A02 = f4z, A03 = f4z;
    float4 A10 = f4z, A11 = f4z, A12 = f4z, A13 = f4z;
    int4   T0 = make_int4(0,0,0,0), T1 = make_int4(0,0,0,0);
    bool   ok0 = false, ok1 = false;
    float4 s_m = f4z, s_c = f4z, s_p = f4z;
    float4 vH  = f4z;

    auto prefetch = [&](int L) {
        const bool zok = ((unsigned)L < 128u);
        ok0 = zok && lv0;
        ok1 = zok && lv1;
        if (ok0) {
            size_t o = (size_t)(L << 12) + off0;
            A00 = in4[co0 + o];
            A01 = in4[co1 + o];
            A02 = in4[co2 + o];
            A03 = in4[co3 + o];
            T0  = tg4[((size_t)b << 19) + o];
        }
        if (ok1) {
            size_t o = (size_t)(L << 12) + off1;
            A10 = in4[co0 + o];
            A11 = in4[co1 + o];
            A12 = in4[co2 + o];
            A13 = in4[co3 + o];
            T1  = tg4[((size_t)b << 19) + o];
        }
    };
    auto op_one = [&](const float4& B0, const float4& B1, const float4& B2,
                      const float4& B3, const int4& T) -> float4 {
        float4 r;
        #define OP1(K)                                                         \
        {                                                                      \
            float vc = B0.K;                                                   \
            float sm = 1.0f + __expf(B1.K - vc) + __expf(B2.K - vc)            \
                            + __expf(B3.K - vc);                               \
            float d  = __builtin_amdgcn_rcpf(sm) - ((T.K == c) ? 1.0f : 0.0f); \
            r.K = d * d;                                                       \
        }
        OP1(x) OP1(y) OP1(z) OP1(w)
        #undef OP1
        return r;
    };
    auto commit = [&](int L) {
        float4* sl = lin + SLOT4(L) * IN_P4;
        float4 v0 = f4z, v1 = f4z;
        if (ok0) v0 = op_one(A00, A01, A02, A03, T0);
        if (ok1) v1 = op_one(A10, A11, A12, A13, T1);
        sl[tid] = v0;
        if (act1) sl[256 + tid] = v1;
    };
    auto s1one = [&](const float4* pzm, const float4* pzc, const float4* pzp,
                     int ci, float ym) -> float4 {
        float4 qC = pzc[ci];
        float4 qU = pzc[ci - 32];
        float4 qD = pzc[ci + 32];
        float4 qm = pzm[ci];
        float4 qp = pzp[ci];
        float lf = __shfl_up(qC.w, 1, 64)   * lmask;
        float rt = __shfl_down(qC.x, 1, 64) * rmask;
        float4 v;
        v.x = fmaxf((qC.x + lf   + qC.y + qU.x + qD.x + qm.x + qp.x) * wk + bs, 0.f) * ym;
        v.y = fmaxf((qC.y + qC.x + qC.z + qU.y + qD.y + qm.y + qp.y) * wk + bs, 0.f) * ym;
        v.z = fmaxf((qC.z + qC.y + qC.w + qU.z + qD.z + qm.z + qp.z) * wk + bs, 0.f) * ym;
        v.w = fmaxf((qC.w + qC.z + rt   + qU.w + qD.w + qm.w + qp.w) * wk + bs, 0.f) * ym;
        return v;
    };
    auto s1_phase = [&](int z) {
        float4* o = ls1 + SLOT2(z) * S1_P4;
        float4 vnew;
        if ((unsigned)z < 128u) {
            const float4* pzm = lin + SLOT4(z - 1) * IN_P4;
            const float4* pzc = lin + SLOT4(z)     * IN_P4;
            const float4* pzp = lin + SLOT4(z + 1) * IN_P4;
            vnew = s1one(pzm, pzc, pzp, tid + 64, 1.f);
            o[tid + 32] = vnew;
            if (sact1) o[so1] = s1one(pzm, pzc, pzp, ci1, m1);
        } else {
            vnew = f4z;
            o[tid + 32] = f4z;
            if (sact1) o[so1] = f4z;
        }
        s_m = s_c; s_c = s_p; s_p = vnew;
    };

    double part = 0.0;

    prefetch(zb - 2); commit(zb - 2);
    prefetch(zb - 1); commit(zb - 1);
    prefetch(zb);     commit(zb);
    prefetch(zb + 1);
    __syncthreads();
    s1_phase(zb - 1);

    for (int L = zb + 1; L <= zb + 17; ++L) {
        commit(L);
        __syncthreads();                    // publishes votes for zp = L-3
        const int zp = L - 3;
        if (zp >= zb && voteArr[zp - zb] != 0)
            dp[((size_t)zp << 12) + go4] = vH;
        if (L <= zb + 16) prefetch(L + 1);
        s1_phase(L - 1);
        const int zo = L - 2;
        if (zo >= zb) {
            const float4* su = ls1 + SLOT2(zo) * S1_P4;
            float4 u4 = su[tid];
            float4 d4 = su[tid + 64];
            float lf = __shfl_up(s_c.w, 1, 64)   * lmask;
            float rt = __shfl_down(s_c.x, 1, 64) * rmask;
            float4 v;
            v.x = fmaxf((s_c.x + lf    + s_c.y + u4.x + d4.x + s_m.x + s_p.x) * wk + bs, 0.f);
            v.y = fmaxf((s_c.y + s_c.x + s_c.z + u4.y + d4.y + s_m.y + s_p.y) * wk + bs, 0.f);
            v.z = fmaxf((s_c.z + s_c.y + s_c.w + u4.z + d4.z + s_m.z + s_p.z) * wk + bs, 0.f);
            v.w = fmaxf((s_c.w + s_c.z + rt    + u4.w + d4.w + s_m.w + s_p.w) * wk + bs, 0.f);
            float pl = c1 * (s_c.x + s_c.y + s_c.z + s_c.w)
                     + c2 * (v.x   + v.y   + v.z   + v.w);
            part += (double)pl;
            bool nzv = (v.x != 0.f) || (v.y != 0.f) || (v.z != 0.f) || (v.w != 0.f);
            if (__any(nzv) && (tid & 63) == 0) atomicOr(&voteArr[zo - zb], 1);
            vH = v;
        }
    }

    __syncthreads();
    if (voteArr[15] != 0) dp[((size_t)(zb + 15) << 12) + go4] = vH;

    #pragma unroll
    for (int off = 32; off > 0; off >>= 1)
        part += __shfl_down(part, off, 64);
    if ((tid & 63) == 0) wsum[tid >> 6] = part;
    __syncthreads();
    if (tid == 0) {
        int mask = 0;
        #pragma unroll
        for (int i = 0; i < 16; ++i) mask |= (voteArr[i] ? 1 : 0) << i;
        flagOut[fid] = mask;
        double tot = (wsum[0] + wsum[1] + wsum[2] + wsum[3]) * (double)weight[bc];
        accs[blockIdx.x] = tot;
    }
}

// ---------------------------------------------------------------------------
// erode4 (R9 structure, R10 scheduling): FOUR fused erosion steps/dispatch.
// NEW: (1) ballot-based activity word -> inactive blocks exit after 9 flag
// loads + 2 barriers; (2) march trimmed to [fa-2, la+8] of the active input
// range (block-uniform) instead of the full 24-plane window. All stage values
// outside the trimmed range are provably zero (activity-word dilations), so
// the zero-initialized register chains and gated LDS reads stay exact.
// ---------------------------------------------------------------------------
#define E4_INP4  512   // 16 rows * 32
#define E4_S1P4  448   // 14 rows * 32
#define E4_S2P4  384   // 12 rows * 32
#define E4_S3P4  320   // 10 rows * 32

__global__ __launch_bounds__(256, 2) void erode4_kernel(
    const float4* __restrict__ src, float4* __restrict__ dst,
    const float* __restrict__ kern, const float* __restrict__ bias,
    const float* __restrict__ weight,
    float c1, float c2, float c3, float c4,
    int store, double* __restrict__ accs,
    const int* __restrict__ flagIn, int* __restrict__ flagOut)
{
    __shared__ float4 lin[4 * E4_INP4];   // 32 KB
    __shared__ float4 ls1[2 * E4_S1P4];   // 14 KB
    __shared__ float4 ls2[2 * E4_S2P4];   // 12 KB
    __shared__ float4 ls3[2 * E4_S3P4];   // 10 KB
    __shared__ double wsum[4];
    __shared__ int    sf[9];
    __shared__ int    voteArr[16];
    __shared__ unsigned sAIn;

    const int tid = threadIdx.x;
    const int bid = ((blockIdx.x & 7) << 7) | (blockIdx.x >> 3);
    const int ty = bid & 15;
    const int tz = (bid >> 4) & 7;
    const int y0 = ty << 3;
    const int zb = tz << 4;
    const int bc = bid >> 7;

    if (tid < 9) {
        int dy = tid % 3 - 1, dz = tid / 3 - 1;
        int yt = ty + dy, zt = tz + dz;
        int f = 0;
        if ((unsigned)yt < 16u && (unsigned)zt < 8u)
            f = flagIn[(bc << 7) | (zt << 4) | yt];
        sf[tid] = f;
    }
    __syncthreads();

    // wave-0 ballot: bit i of aIn <-> input plane zb-4+i has a nonzero
    bool abit = false;
    if (tid < 24) {
        int L = zb - 4 + tid;
        if ((unsigned)L < 128u) {
            int zi = (L >> 4) - tz + 1;
            int m  = sf[zi * 3] | sf[zi * 3 + 1] | sf[zi * 3 + 2];
            abit = (m >> (L & 15)) & 1;
        }
    }
    unsigned long long bal = __ballot(abit);
    if (tid == 0) sAIn = (unsigned)bal;
    __syncthreads();
    const unsigned aIn = sAIn;
    if (aIn == 0) { if (tid == 0) flagOut[bid] = 0; return; }

    // z-validity clamp for dilations (bit i valid iff 0 <= zb-4+i < 128)
    unsigned zc = 0xFFFFFFu;
    if (zb == 0)   zc &= 0xFFFFF0u;
    if (zb == 112) zc &= 0x0FFFFFu;
    const unsigned a1 = (aIn | aIn << 1 | aIn >> 1) & zc & 0x7FFFFEu;
    const unsigned a2 = (a1  | a1  << 1 | a1  >> 1) & zc & 0x3FFFFCu;
    const unsigned a3 = (a2  | a2  << 1 | a2  >> 1) & zc & 0x1FFFF8u;
    const unsigned a4 = (a3  | a3  << 1 | a3  >> 1) & zc & 0x0FFFF0u;

    if (tid < 16) voteArr[tid] = 0;     // published by first in-loop barrier

    // trimmed march range (block-uniform): covers all commits (fa-1..la+1),
    // warm-up slots (2 zero commits), and all stage evals (last s4 at la+8)
    const int fa  = __builtin_ctz(aIn);
    const int la  = 31 - __builtin_clz(aIn);
    const int loL = zb - 4 + (fa > 2 ? fa - 2 : 0);
    const int hiL = zb - 4 + (la + 8 < 23 ? la + 8 : 23);

    const float4* sp = src + ((size_t)bc << 19);
    float4*       dp = dst + ((size_t)bc << 19);
    const float wk = kern[13];
    const float bs = bias[bc & 3];

    const int col  = tid & 31;
    const int trow = tid >> 5;
    const int g    = trow;

    const int  gy0 = y0 - 4 + trow;
    const int  gy1 = y0 + 4 + trow;
    const bool lv0 = ((unsigned)gy0 < 128u);
    const bool lv1 = ((unsigned)gy1 < 128u);
    const int  off0 = (lv0 ? gy0 : 0) * 32 + col;
    const int  off1 = (lv1 ? gy1 : 0) * 32 + col;
    const int  yd0 = ((unsigned)((gy0 >> 3) - ty + 1) < 3u) ? ((gy0 >> 3) - ty + 1) : 1;
    const int  yd1 = ((unsigned)((gy1 >> 3) - ty + 1) < 3u) ? ((gy1 >> 3) - ty + 1) : 1;

    const int   r1  = (g < 3) ? g : g + 8;             // s1 rows {0,1,2,11,12,13}
    const float ym1 = ((unsigned)(y0 - 3 + r1) < 128u) ? 1.f : 0.f;
    const int   ci1 = (r1 + 1) * 32 + col;
    const int   R2  = (g < 2) ? g : g + 8;             // s2 rows {0,1,10,11}
    const float ym2 = ((unsigned)(y0 - 2 + R2) < 128u) ? 1.f : 0.f;
    const int   ci2 = (R2 + 2) * 32 + col;
    const int   S3  = g * 9;                           // s3 rows {0,9}
    const float ym3 = ((unsigned)(y0 - 1 + S3) < 128u) ? 1.f : 0.f;
    const int   ci3 = (S3 + 3) * 32 + col;

    const float lmask = (col == 0)  ? 0.f : 1.f;
    const float rmask = (col == 31) ? 0.f : 1.f;
    const int   go4  = (y0 + trow) * 32 + col;

    const float4 f4z = make_float4(0.f, 0.f, 0.f, 0.f);
    float4 pf0 = f4z, pf1 = f4z;
    float4 p1m=f4z,p1c=f4z,p1p=f4z;
    float4 p2m=f4z,p2c=f4z,p2p=f4z;
    float4 p3m=f4z,p3c=f4z,p3p=f4z;
    float4 o1m=f4z,o1c=f4z,o1p=f4z;
    float4 q1m=f4z,q1c=f4z,q1p=f4z;
    float4 q2m=f4z,q2c=f4z,q2p=f4z;
    float4 vH = f4z;
    double part = 0.0;

    auto st7 = [&](const float4& zm, const float4& cc, const float4& zp,
                   const float4& u, const float4& d, float ym) -> float4 {
        float lf = __shfl_up(cc.w, 1, 64)   * lmask;
        float rt = __shfl_down(cc.x, 1, 64) * rmask;
        float4 v;
        v.x = fmaxf((cc.x + lf   + cc.y + u.x + d.x + zm.x + zp.x) * wk + bs, 0.f) * ym;
        v.y = fmaxf((cc.y + cc.x + cc.z + u.y + d.y + zm.y + zp.y) * wk + bs, 0.f) * ym;
        v.z = fmaxf((cc.z + cc.y + cc.w + u.z + d.z + zm.z + zp.z) * wk + bs, 0.f) * ym;
        v.w = fmaxf((cc.w + cc.z + rt   + u.w + d.w + zm.w + zp.w) * wk + bs, 0.f) * ym;
        return v;
    };
    auto s1at = [&](int z, int ci, float ym) -> float4 {
        const float4* pzm = lin + SLOT4(z - 1) * E4_INP4;
        const float4* pzc = lin + SLOT4(z)     * E4_INP4;
        const float4* pzp = lin + SLOT4(z + 1) * E4_INP4;
        return st7(pzm[ci], pzc[ci], pzp[ci], pzc[ci - 32], pzc[ci + 32], ym);
    };
    auto prefetch = [&](int L) {
        pf0 = f4z; pf1 = f4z;
        if (L >= zb - 4 && L <= zb + 19 && (unsigned)L < 128u) {
            const int zi = (L >> 4) - tz + 1;
            const int sh = L & 15;
            const float4* zp = sp + ((size_t)L << 12);
            if (lv0 && ((sf[zi * 3 + yd0] >> sh) & 1)) pf0 = zp[off0];
            if (lv1 && ((sf[zi * 3 + yd1] >> sh) & 1)) pf1 = zp[off1];
        }
    };
    auto commit = [&](int L) {
        float4* sl = lin + SLOT4(L) * E4_INP4;
        sl[trow * 32 + col]       = pf0;
        sl[(trow + 8) * 32 + col] = pf1;
    };

    prefetch(loL);
    for (int L = loL; L <= hiL; ++L) {
        commit(L);
        __syncthreads();                    // publishes votes for zs = L-5
        const int zs = L - 5;
        if (store && zs >= zb && voteArr[zs - zb] != 0)
            dp[((size_t)zs << 12) + go4] = vH;
        if (L < hiL) prefetch(L + 1);

        // ---- s1(z = L-1) ----
        {
            const int z = L - 1, ib = z - (zb - 4);
            float4 vp = f4z, vo = f4z, vq = f4z;
            if ((unsigned)ib < 24u && ((a1 >> ib) & 1)) {
                vp = s1at(z, (trow + 4) * 32 + col, 1.f);
                float4* o = ls1 + SLOT2(z) * E4_S1P4;
                if (tid < 192) o[r1 * 32 + col] = s1at(z, ci1, ym1);
                if (tid < 128) vo = s1at(z, ci2, ym2);
                if (tid < 64)  vq = s1at(z, ci3, ym3);
                o[(trow + 3) * 32 + col] = vp;
                if (z >= zb && z <= zb + 15)
                    part += (double)(c1 * (vp.x + vp.y + vp.z + vp.w));
            }
            p1m = p1c; p1c = p1p; p1p = vp;
            o1m = o1c; o1c = o1p; o1p = vo;
            q1m = q1c; q1c = q1p; q1p = vq;
        }
        // ---- s2(z = L-2) ----
        {
            const int z = L - 2, ib = z - (zb - 4);
            float4 vp = f4z, vq = f4z;
            if ((unsigned)ib < 24u && ((a2 >> ib) & 1)) {
                const bool l1 = ((a1 >> ib) & 1);
                const float4* s1p_ = ls1 + SLOT2(z) * E4_S1P4;
                float4 u = l1 ? s1p_[(trow + 2) * 32 + col] : f4z;
                float4 d = l1 ? s1p_[(trow + 4) * 32 + col] : f4z;
                vp = st7(p1m, p1c, p1p, u, d, 1.f);
                float4* o = ls2 + SLOT2(z) * E4_S2P4;
                if (tid < 128) {
                    float4 u2 = l1 ? s1p_[R2 * 32 + col]       : f4z;
                    float4 d2 = l1 ? s1p_[(R2 + 2) * 32 + col] : f4z;
                    o[R2 * 32 + col] = st7(o1m, o1c, o1p, u2, d2, ym2);
                }
                if (tid < 64) {
                    float4 u3 = l1 ? s1p_[(S3 + 1) * 32 + col] : f4z;
                    float4 d3 = l1 ? s1p_[(S3 + 3) * 32 + col] : f4z;
                    vq = st7(q1m, q1c, q1p, u3, d3, ym3);
                }
                o[(trow + 2) * 32 + col] = vp;
                if (z >= zb && z <= zb + 15)
                    part += (double)(c2 * (vp.x + vp.y + vp.z + vp.w));
            }
            p2m = p2c; p2c = p2p; p2p = vp;
            q2m = q2c; q2c = q2p; q2p = vq;
        }
        // ---- s3(z = L-3) ----
        {
            const int z = L - 3, ib = z - (zb - 4);
            float4 vp = f4z;
            if ((unsigned)ib < 24u && ((a3 >> ib) & 1)) {
                const bool l2 = ((a2 >> ib) & 1);
                const float4* s2p_ = ls2 + SLOT2(z) * E4_S2P4;
                float4 u = l2 ? s2p_[(trow + 1) * 32 + col] : f4z;
                float4 d = l2 ? s2p_[(trow + 3) * 32 + col] : f4z;
                vp = st7(p2m, p2c, p2p, u, d, 1.f);
                float4* o = ls3 + SLOT2(z) * E4_S3P4;
                if (tid < 64) {
                    float4 u3 = l2 ? s2p_[S3 * 32 + col]       : f4z;
                    float4 d3 = l2 ? s2p_[(S3 + 2) * 32 + col] : f4z;
                    o[S3 * 32 + col] = st7(q2m, q2c, q2p, u3, d3, ym3);
                }
                o[(trow + 1) * 32 + col] = vp;
                if (z >= zb && z <= zb + 15)
                    part += (double)(c3 * (vp.x + vp.y + vp.z + vp.w));
            }
            p3m = p3c; p3c = p3p; p3p = vp;
        }
        // ---- s4(z = L-4) : owned output ----
        {
            const int z = L - 4, ib = z - (zb - 4);
            float4 v = f4z;
            if ((unsigned)ib < 24u && ((a4 >> ib) & 1)) {
                const bool l3 = ((a3 >> ib) & 1);
                const float4* s3p_ = ls3 + SLOT2(z) * E4_S3P4;
                float4 u = l3 ? s3p_[trow * 32 + col]       : f4z;
                float4 d = l3 ? s3p_[(trow + 2) * 32 + col] : f4z;
                v = st7(p3m, p3c, p3p, u, d, 1.f);
                part += (double)(c4 * (v.x + v.y + v.z + v.w));
                bool nzv = (v.x != 0.f) || (v.y != 0.f) || (v.z != 0.f) || (v.w != 0.f);
                if (__any(nzv) && (tid & 63) == 0) atomicOr(&voteArr[z - zb], 1);
            }
            vH = v;
        }
    }

    // flush the one pending deferred store (plane computed at L = hiL)
    __syncthreads();
    {
        const int hp = hiL - 4;             // <= zb+15 by construction
        if (store && hp >= zb && voteArr[hp - zb] != 0)
            dp[((size_t)hp << 12) + go4] = vH;
    }

    #pragma unroll
    for (int off = 32; off > 0; off >>= 1)
        part += __shfl_down(part, off, 64);
    if ((tid & 63) == 0) wsum[tid >> 6] = part;
    __syncthreads();
    if (tid == 0) {
        int mask = 0;
        #pragma unroll
        for (int i = 0; i < 16; ++i) mask |= (voteArr[i] ? 1 : 0) << i;
        flagOut[bid] = mask;
        double tot = (wsum[0] + wsum[1] + wsum[2] + wsum[3]) * (double)weight[bc];
        atomicAdd(&accs[bid], tot);
    }
}

// Reduce the NACC per-block accumulators -> scalar mean.
__global__ __launch_bounds__(1024) void finalize_kernel(
    const double* __restrict__ accs, float* __restrict__ out)
{
    __shared__ double wsum[16];
    double v = accs[threadIdx.x];
    #pragma unroll
    for (int off = 32; off > 0; off >>= 1)
        v += __shfl_down(v, off, 64);
    int lane = threadIdx.x & 63;
    int wid  = threadIdx.x >> 6;
    if (lane == 0) wsum[wid] = v;
    __syncthreads();
    if (threadIdx.x == 0) {
        double tot = 0.0;
        #pragma unroll
        for (int i = 0; i < 16; ++i) tot += wsum[i];
        out[0] = (float)(tot / (double)NTOT);
    }
}

extern "C" void kernel_launch(void* const* d_in, const int* in_sizes, int n_in,
                              void* d_out, int out_size, void* d_ws, size_t ws_size,
                              hipStream_t stream) {
    const float* in     = (const float*)d_in[0];
    const int*   tgt    = (const int*)d_in[1];
    const float* weight = (const float*)d_in[2];
    const float* kern   = (const float*)d_in[3];
    const float* bias   = (const float*)d_in[4];
    float* out = (float*)d_out;

    char* ws = (char*)d_ws;
    float*  buf0   = (float*)ws;
    float*  buf1   = (float*)(ws + (size_t)NTOT * sizeof(float));
    double* accs   = (double*)(ws + (size_t)NTOT * 2 * sizeof(float));
    int*    flagsA = (int*)(ws + (size_t)NTOT * 2 * sizeof(float) + NACC * sizeof(double));
    int*    flagsB = flagsA + NACC;

    // 1) fused softmax+square+erode^2 (steps 1-2): in -> buf0, masks -> flagsA
    fused_sm_erode2_kernel<<<1024, 256, 0, stream>>>(
        in, tgt, (float4*)buf0, kern, bias, weight, 1.0f, 4.0f, accs, flagsA);

    // 2) erode^4 (steps 3-6): buf0 -> buf1, masks flagsA -> flagsB
    erode4_kernel<<<1024, 256, 0, stream>>>(
        (const float4*)buf0, (float4*)buf1, kern, bias, weight,
        9.0f, 16.0f, 25.0f, 36.0f, 1, accs, flagsA, flagsB);

    // 3) erode^4 (steps 7-10): buf1, no store
    erode4_kernel<<<1024, 256, 0, stream>>>(
        (const float4*)buf1, (float4*)buf0, kern, bias, weight,
        49.0f, 64.0f, 81.0f, 100.0f, 0, accs, flagsB, flagsA);

    // 4) reduce + mean
    finalize_kernel<<<1, 1024, 0, stream>>>(accs, out);
}